// Round 11
// baseline (268.185 us; speedup 1.0000x reference)
//
#include <hip/hip_runtime.h>
#include <cstring>
#include <cmath>
#include <cstdint>

#define N_TOK 65536
#define DIN 128
#define HD 64
#define TN 12
#define ON 3
#define NHOPS 4
#define TPB 256
#define TOKB 128         // tokens per k_hop block (4 waves x 32 tokens)
#define NCAT 13

typedef __attribute__((ext_vector_type(8))) short short8v;     // 8 bf16 frag
typedef __attribute__((ext_vector_type(4))) float f32x4;
typedef __attribute__((ext_vector_type(4))) unsigned short ushort4v;
typedef __attribute__((ext_vector_type(8))) unsigned short ushort8v;

struct HopConst {
  float w[TN][ON];
  unsigned ck0, ck1;
  int last_hop;
};

// ---- threefry2x32 (exact JAX semantics) ----
__host__ __device__ __forceinline__ void tf2x32(unsigned k0, unsigned k1,
                                                unsigned x0, unsigned x1,
                                                unsigned& o0, unsigned& o1) {
  unsigned ks2 = k0 ^ k1 ^ 0x1BD11BDAu;
  x0 += k0; x1 += k1;
#define TFR(r) { x0 += x1; x1 = (x1 << (r)) | (x1 >> (32 - (r))); x1 ^= x0; }
  TFR(13) TFR(15) TFR(26) TFR(6)
  x0 += k1;  x1 += ks2 + 1u;
  TFR(17) TFR(29) TFR(16) TFR(24)
  x0 += ks2; x1 += k0 + 2u;
  TFR(13) TFR(15) TFR(26) TFR(6)
  x0 += k0;  x1 += k1 + 3u;
  TFR(17) TFR(29) TFR(16) TFR(24)
  x0 += k1;  x1 += ks2 + 4u;
  TFR(13) TFR(15) TFR(26) TFR(6)
  x0 += ks2; x1 += k0 + 5u;
#undef TFR
  o0 = x0; o1 = x1;
}
__host__ __device__ __forceinline__ unsigned tf_bits32(unsigned k0, unsigned k1, unsigned j) {
  unsigned o0, o1;
  tf2x32(k0, k1, 0u, j, o0, o1);
  return o0 ^ o1;
}

// ---- bf16x3 splitting ----
__host__ __device__ __forceinline__ unsigned short bf16r(float v) {
  unsigned u = __builtin_bit_cast(unsigned, v);
  return (unsigned short)((u + 0x7fffu + ((u >> 16) & 1u)) >> 16);
}
__host__ __device__ __forceinline__ float bf2f(unsigned short s) {
  return __builtin_bit_cast(float, ((unsigned)s) << 16);
}
__host__ __device__ __forceinline__ void split3(float v, unsigned short& a,
                                                unsigned short& b, unsigned short& c) {
  a = bf16r(v); float r = v - bf2f(a);
  b = bf16r(r); r -= bf2f(b);
  c = bf16r(r);
}

// ---- kernels ----

// init: states = x @ proj_W + proj_b via bf16x3 MFMA; tempers/done/histogram
__global__ __launch_bounds__(512, 4) void k_init(
    const float* __restrict__ x, const unsigned short* __restrict__ pjf,
    const float* __restrict__ pb, const int* __restrict__ itemp,
    float* __restrict__ states, int* __restrict__ tempers,
    int* __restrict__ done, int* __restrict__ cnt0)
{
  __shared__ unsigned short sX[3 * 64 * 128];  // 48KB x splits
  __shared__ float sOut[64 * 64];              // 16KB out
  __shared__ int lcnt[TN];
  const int tid = threadIdx.x;
  const int lane = tid & 63;
  const int w = __builtin_amdgcn_readfirstlane(tid >> 6);
  const int mgrp = w & 1, ngrp = w >> 1;       // 2 feat-halves x 4 tok-quarters
  const int bstart = blockIdx.x * 64;

  // stage x (coalesced): thread = (tok=tid>>3, c0=tid&7), 16 k each
  {
    const int tok = tid >> 3, c0 = tid & 7;
    const float* xr = x + (size_t)(bstart + tok) * DIN + c0 * 16;
    float v[16];
    #pragma unroll
    for (int q = 0; q < 4; ++q) {
      const float4 f = *(const float4*)(xr + q * 4);
      v[q*4] = f.x; v[q*4+1] = f.y; v[q*4+2] = f.z; v[q*4+3] = f.w;
    }
    unsigned short sp[3][16];
    #pragma unroll
    for (int i = 0; i < 16; ++i) split3(v[i], sp[0][i], sp[1][i], sp[2][i]);
    #pragma unroll
    for (int s = 0; s < 3; ++s)
      #pragma unroll
      for (int jj = 0; jj < 2; ++jj) {
        ushort8v u;
        #pragma unroll
        for (int i = 0; i < 8; ++i) u[i] = sp[s][jj * 8 + i];
        const int chunk = (2 * c0 + jj) ^ (tok & 7);
        *(ushort8v*)(sX + s * 8192 + tok * 128 + chunk * 8) = u;
      }
  }
  if (tid < TN) lcnt[tid] = 0;
  __syncthreads();

  const f32x4 zf = {0.0f, 0.0f, 0.0f, 0.0f};
  const int tok16 = (lane & 15) + 16 * ngrp;
  short8v bf[3][4];
  #pragma unroll
  for (int s = 0; s < 3; ++s)
    #pragma unroll
    for (int kc = 0; kc < 4; ++kc) {
      const int chunk = (4 * kc + (lane >> 4)) ^ (tok16 & 7);
      bf[s][kc] = *(const short8v*)(sX + s * 8192 + tok16 * 128 + chunk * 8);
    }
  f32x4 acc[2] = {zf, zf};
  #pragma unroll
  for (int sw = 0; sw < 3; ++sw) {
    short8v a[2][4];
    #pragma unroll
    for (int mt = 0; mt < 2; ++mt)
      #pragma unroll
      for (int kc = 0; kc < 4; ++kc)
        a[mt][kc] = *(const short8v*)(pjf +
            (size_t)((sw * 4 + (2 * mgrp + mt)) * 4 + kc) * 512 + lane * 8);
    #pragma unroll
    for (int sa = 0; sa < 3; ++sa) {
      if (sw + sa > 2) continue;
      #pragma unroll
      for (int mt = 0; mt < 2; ++mt)
        #pragma unroll
        for (int kc = 0; kc < 4; ++kc)
          acc[mt] = __builtin_amdgcn_mfma_f32_16x16x32_bf16(
              a[mt][kc], bf[sa][kc], acc[mt], 0, 0, 0);
    }
  }

  // D + bias -> swizzled f32 LDS
  #pragma unroll
  for (int mt = 0; mt < 2; ++mt) {
    const int mt2 = 2 * mgrp + mt;
    const int j0 = 16 * mt2 + 4 * (lane >> 4);
    const float4 bv = *(const float4*)(pb + j0);
    const float bb[4] = {bv.x, bv.y, bv.z, bv.w};
    f32x4 vv;
    #pragma unroll
    for (int r = 0; r < 4; ++r) vv[r] = acc[mt][r] + bb[r];
    const int chunk = (4 * mt2 + (lane >> 4)) ^ (tok16 & 15);
    *(f32x4*)(sOut + tok16 * 64 + chunk * 4) = vv;
  }
  __syncthreads();

  // coalesced states write-back
  {
    const int tok = tid >> 3, c0 = tid & 7;
    const int n = bstart + tok;
    float* wr = states + (size_t)n * HD;
    #pragma unroll
    for (int q = 0; q < 2; ++q) {
      const int c = c0 + 8 * q;
      const int cs = c ^ (tok & 15);
      *(float4*)(wr + c * 4) = *(const float4*)(sOut + tok * 64 + cs * 4);
    }
  }
  if (tid < 64) {
    const int n = bstart + tid;
    const int t = itemp[n];
    tempers[n] = t;
    done[n] = 0;
    atomicAdd(&lcnt[t], 1);
  }
  __syncthreads();
  if (tid < TN && lcnt[tid] > 0) atomicAdd(&cnt0[tid], lcnt[tid]);
}

// one-time: split weights to bf16x3 in MFMA A-frag order.
// A-frag: frag(s, mtile, kc, lane) holds A[m=16*mtile+(lane&15)][k=32*kc+8*(lane>>4)+i]
__global__ __launch_bounds__(TPB) void k_wprep(
    const float* __restrict__ W1, const float* __restrict__ W2,
    const float* __restrict__ rW1, const float* __restrict__ rW2,
    const float* __restrict__ pjW, const float* __restrict__ pdW,
    unsigned short* __restrict__ w1f, unsigned short* __restrict__ w2f,
    unsigned short* __restrict__ rw1f, unsigned short* __restrict__ rw2f,
    unsigned short* __restrict__ pjf, unsigned short* __restrict__ pwf)
{
  const int idx = blockIdx.x * TPB + threadIdx.x;
  const int NU1 = TN * ON * 4 * 2 * 64;   // 18432
  const int NU2 = 4 * 2 * 64;             // 512
  const int NU3 = 2 * 64;                 // 128
  const int NU4 = 4 * 4 * 64;             // 1024 proj_W (4 mt x 4 kc)
  const int NU5 = 8 * 2 * 64;             // 1024 pred_W (8 mt x 2 kc)
  if (idx < NU1) {
    const int lane = idx & 63, kc = (idx >> 6) & 1, mt = (idx >> 7) & 3, mat = idx >> 9;
    const int j = 16 * mt + (lane & 15);
    const int h0 = 32 * kc + 8 * (lane >> 4);
    const float* s1 = W1 + (size_t)mat * 4096;
    const float* s2 = W2 + (size_t)mat * 4096;
    #pragma unroll
    for (int i = 0; i < 8; ++i) {
      unsigned short a0, a1, a2;
      const size_t base = (size_t)mat * 12288 + (size_t)(mt * 2 + kc) * 512 + lane * 8 + i;
      split3(s1[(h0 + i) * 64 + j], a0, a1, a2);
      w1f[base] = a0; w1f[base + 4096] = a1; w1f[base + 8192] = a2;
      split3(s2[(h0 + i) * 64 + j], a0, a1, a2);
      w2f[base] = a0; w2f[base + 4096] = a1; w2f[base + 8192] = a2;
    }
  } else if (idx < NU1 + NU2) {
    const int u = idx - NU1;
    const int lane = u & 63, kc = (u >> 6) & 1, mt = (u >> 7) & 3;
    const int j = 16 * mt + (lane & 15);
    const int h0 = 32 * kc + 8 * (lane >> 4);
    #pragma unroll
    for (int i = 0; i < 8; ++i) {
      unsigned short a0, a1, a2;
      const size_t base = (size_t)(mt * 2 + kc) * 512 + lane * 8 + i;
      split3(rW1[(h0 + i) * 64 + j], a0, a1, a2);
      rw1f[base] = a0; rw1f[base + 4096] = a1; rw1f[base + 8192] = a2;
    }
  } else if (idx < NU1 + NU2 + NU3) {
    const int u = idx - NU1 - NU2;
    const int lane = u & 63, kc = (u >> 6) & 1;
    const int c = lane & 15;
    const int h0 = 32 * kc + 8 * (lane >> 4);
    #pragma unroll
    for (int i = 0; i < 8; ++i) {
      unsigned short a0, a1, a2;
      const float v = (c < NCAT) ? rW2[(h0 + i) * NCAT + c] : 0.0f;
      split3(v, a0, a1, a2);
      const size_t base = (size_t)kc * 512 + lane * 8 + i;
      rw2f[base] = a0; rw2f[base + 1024] = a1; rw2f[base + 2048] = a2;
    }
  } else if (idx < NU1 + NU2 + NU3 + NU4) {
    const int u = idx - (NU1 + NU2 + NU3);
    const int lane = u & 63, kc = (u >> 6) & 3, mt = u >> 8;
    const int j = 16 * mt + (lane & 15);
    const int k0 = 32 * kc + 8 * (lane >> 4);
    #pragma unroll
    for (int i = 0; i < 8; ++i) {
      unsigned short a0, a1, a2;
      split3(pjW[(size_t)(k0 + i) * 64 + j], a0, a1, a2);
      const size_t base = (size_t)(mt * 4 + kc) * 512 + lane * 8 + i;
      pjf[base] = a0; pjf[base + 8192] = a1; pjf[base + 16384] = a2;
    }
  } else if (idx < NU1 + NU2 + NU3 + NU4 + NU5) {
    const int u = idx - (NU1 + NU2 + NU3 + NU4);
    const int lane = u & 63, kc = (u >> 6) & 1, mt = u >> 7;
    const int d = 16 * mt + (lane & 15);
    const int h0 = 32 * kc + 8 * (lane >> 4);
    #pragma unroll
    for (int i = 0; i < 8; ++i) {
      unsigned short a0, a1, a2;
      split3(pdW[(size_t)(h0 + i) * 128 + d], a0, a1, a2);
      const size_t base = (size_t)(mt * 2 + kc) * 512 + lane * 8 + i;
      pwf[base] = a0; pwf[base + 8192] = a1; pwf[base + 16384] = a2;
    }
  }
}

__global__ void k_prefix(const int* __restrict__ cnt, int* __restrict__ offp) {
  if (threadIdx.x == 0 && blockIdx.x == 0) {
    int o = 0;
    for (int t = 0; t < TN; ++t) { offp[t] = o; o += (cnt[t] + TOKB - 1) & ~(TOKB - 1); }
    offp[TN] = o;
  }
}

__global__ __launch_bounds__(TPB) void k_scatter(
    const int* __restrict__ tempers, const int* __restrict__ done,
    const int* __restrict__ offp, int* __restrict__ cursor, int* __restrict__ compact)
{
  __shared__ int lcnt[TN], lbase[TN];
  const int tid = threadIdx.x;
  if (tid < TN) lcnt[tid] = 0;
  __syncthreads();
  const int n = blockIdx.x * TPB + tid;
  int t = -1, lpos = 0;
  if (!done[n]) { t = tempers[n]; lpos = atomicAdd(&lcnt[t], 1); }
  __syncthreads();
  if (tid < TN && lcnt[tid] > 0) lbase[tid] = atomicAdd(&cursor[tid], lcnt[tid]);
  __syncthreads();
  if (t >= 0) compact[offp[t] + lbase[t] + lpos] = n;
}

// ---- wave-local helpers (32 tokens x 64 features per wave) ----
// scratch: per split s (2048 u16): idx = token*64 + chunk*8 + (f&7)

__device__ __forceinline__ void load_bf2(const unsigned short* src, int lane,
                                         short8v bf[3][2][2]) {
  const int n = lane & 15, g = lane >> 4;
  #pragma unroll
  for (int s = 0; s < 3; ++s)
    #pragma unroll
    for (int nt = 0; nt < 2; ++nt)
      #pragma unroll
      for (int kc = 0; kc < 2; ++kc) {
        const int chunk = (4 * kc + g) ^ (n & 7);
        bf[s][nt][kc] = *(const short8v*)(src + s * 2048 + (n + 16 * nt) * 64 + chunk * 8);
      }
}

// 6-pass bf16x3 MFMA, 4 m-tiles x 2 n-tiles
__device__ __forceinline__ void mfma_allB(const unsigned short* __restrict__ Ag,
                                          const short8v bf[3][2][2], int lane,
                                          f32x4 acc[4][2]) {
  #pragma unroll
  for (int sw = 0; sw < 3; ++sw) {
    short8v a[4][2];
    #pragma unroll
    for (int mt = 0; mt < 4; ++mt)
      #pragma unroll
      for (int kc = 0; kc < 2; ++kc)
        a[mt][kc] = *(const short8v*)(Ag +
            (size_t)((sw * 4 + mt) * 2 + kc) * 512 + lane * 8);
    #pragma unroll
    for (int sa = 0; sa < 3; ++sa) {
      if (sw + sa > 2) continue;
      #pragma unroll
      for (int mt = 0; mt < 4; ++mt)
        #pragma unroll
        for (int nt = 0; nt < 2; ++nt)
          #pragma unroll
          for (int kc = 0; kc < 2; ++kc)
            acc[mt][nt] = __builtin_amdgcn_mfma_f32_16x16x32_bf16(
                a[mt][kc], bf[sa][nt][kc], acc[mt][nt], 0, 0, 0);
    }
  }
}

// bias + relu + split3 -> wave-local swizzled scratch (both n-tiles)
__device__ __forceinline__ void store8_rb(const f32x4 acc[4][2], const float* __restrict__ bias,
                                          unsigned short* dst, int lane) {
  const int n = lane & 15, g = lane >> 4;
  #pragma unroll
  for (int mt = 0; mt < 4; ++mt) {
    const float4 bv = *(const float4*)(bias + 16 * mt + 4 * g);
    const float bb[4] = {bv.x, bv.y, bv.z, bv.w};
    #pragma unroll
    for (int nt = 0; nt < 2; ++nt) {
      ushort4v u0, u1, u2;
      #pragma unroll
      for (int r = 0; r < 4; ++r) {
        const float v = fmaxf(acc[mt][nt][r] + bb[r], 0.0f);
        unsigned short a, b, c;
        split3(v, a, b, c);
        u0[r] = a; u1[r] = b; u2[r] = c;
      }
      const int idx = (n + 16 * nt) * 64 + ((2 * mt + (g >> 1)) ^ (n & 7)) * 8 + 4 * (g & 1);
      *(ushort4v*)(dst + idx) = u0;
      *(ushort4v*)(dst + 2048 + idx) = u1;
      *(ushort4v*)(dst + 4096 + idx) = u2;
    }
  }
}

// raw split3 -> scratch (no bias/relu) for routing input
__device__ __forceinline__ void store8_raw(const f32x4 acc[4][2], unsigned short* dst, int lane) {
  const int n = lane & 15, g = lane >> 4;
  #pragma unroll
  for (int mt = 0; mt < 4; ++mt)
    #pragma unroll
    for (int nt = 0; nt < 2; ++nt) {
      ushort4v u0, u1, u2;
      #pragma unroll
      for (int r = 0; r < 4; ++r) {
        unsigned short a, b, c;
        split3(acc[mt][nt][r], a, b, c);
        u0[r] = a; u1[r] = b; u2[r] = c;
      }
      const int idx = (n + 16 * nt) * 64 + ((2 * mt + (g >> 1)) ^ (n & 7)) * 8 + 4 * (g & 1);
      *(ushort4v*)(dst + idx) = u0;
      *(ushort4v*)(dst + 2048 + idx) = u1;
      *(ushort4v*)(dst + 4096 + idx) = u2;
    }
}

// main per-hop kernel: barrier-free per-wave pipeline, 32 tokens/wave
__global__ __launch_bounds__(TPB, 2) void k_hop(
    float* __restrict__ states, int* __restrict__ tempers, int* __restrict__ done,
    const int* __restrict__ compact, const int* __restrict__ cnt,
    const int* __restrict__ offp,
    const unsigned short* __restrict__ w1f, const float* __restrict__ b1,
    const unsigned short* __restrict__ w2f, const float* __restrict__ b2,
    const unsigned short* __restrict__ rw1f, const float* __restrict__ rb1,
    const unsigned short* __restrict__ rw2f, const float* __restrict__ rb2,
    int* __restrict__ cnt_next, HopConst hc)
{
  __shared__ unsigned short scr[4][6144];   // 48KB: 12KB private scratch per wave
  __shared__ int lcnt[TN];

  const int tid = threadIdx.x;
  const int lane = tid & 63;
  const int wid = __builtin_amdgcn_readfirstlane(tid >> 6);
  unsigned short* ws = scr[wid];
  const int bstart = blockIdx.x * TOKB;
  if (bstart >= offp[TN]) return;
  if (tid < TN) lcnt[tid] = 0;
  int tt = 0;
  #pragma unroll
  for (int i = 1; i < TN; ++i) if (bstart >= offp[i]) tt = i;
  const int t = __builtin_amdgcn_readfirstlane(tt);
  const int cntt = cnt[t];
  const int n = lane & 15, g = lane >> 4;

  int tok[2]; bool act[2];
  #pragma unroll
  for (int nt = 0; nt < 2; ++nt) {
    const int pos = bstart + wid * 32 + nt * 16 + n;
    act[nt] = (pos - offp[t]) < cntt;
    tok[nt] = compact[act[nt] ? pos : offp[t]];
  }

  // ---- stage states in-register: lane loads its tokens' k-slices ----
  short8v bx[3][2][2];
  #pragma unroll
  for (int nt = 0; nt < 2; ++nt) {
    const float* sr = states + (size_t)tok[nt] * HD;
    float va[8], vb[8];
    #pragma unroll
    for (int q = 0; q < 2; ++q) {
      const float4 f0 = *(const float4*)(sr + 8 * g + q * 4);
      const float4 f1 = *(const float4*)(sr + 32 + 8 * g + q * 4);
      va[q*4] = f0.x; va[q*4+1] = f0.y; va[q*4+2] = f0.z; va[q*4+3] = f0.w;
      vb[q*4] = f1.x; vb[q*4+1] = f1.y; vb[q*4+2] = f1.z; vb[q*4+3] = f1.w;
    }
    unsigned short sa_[3][8], sb_[3][8];
    #pragma unroll
    for (int i = 0; i < 8; ++i) {
      split3(va[i], sa_[0][i], sa_[1][i], sa_[2][i]);
      split3(vb[i], sb_[0][i], sb_[1][i], sb_[2][i]);
    }
    #pragma unroll
    for (int s = 0; s < 3; ++s) {
      short8v u0, u1;
      #pragma unroll
      for (int i = 0; i < 8; ++i) { u0[i] = (short)sa_[s][i]; u1[i] = (short)sb_[s][i]; }
      bx[s][nt][0] = u0; bx[s][nt][1] = u1;
    }
  }
  __syncthreads();   // lcnt init visible before any sampling adds

  const f32x4 zf = {0.0f, 0.0f, 0.0f, 0.0f};
  f32x4 out8[4][2] = {{zf, zf}, {zf, zf}, {zf, zf}, {zf, zf}};

  #pragma unroll 1
  for (int o = 0; o < ON; ++o) {
    const int mat = t * ON + o;
    f32x4 acc[4][2] = {{zf, zf}, {zf, zf}, {zf, zf}, {zf, zf}};
    mfma_allB(w1f + (size_t)mat * 12288, bx, lane, acc);
    store8_rb(acc, b1 + mat * 64, ws, lane);          // h1 splits -> wave scratch
    short8v bh[3][2][2];
    load_bf2(ws, lane, bh);                           // lgkmcnt-ordered, wave-local
    f32x4 acc2[4][2] = {{zf, zf}, {zf, zf}, {zf, zf}, {zf, zf}};
    mfma_allB(w2f + (size_t)mat * 12288, bh, lane, acc2);
    const float wo = hc.w[t][o];
    #pragma unroll
    for (int mt = 0; mt < 4; ++mt) {
      const float4 bv = *(const float4*)(b2 + mat * 64 + 16 * mt + 4 * g);
      const float bb[4] = {bv.x, bv.y, bv.z, bv.w};
      #pragma unroll
      for (int nt = 0; nt < 2; ++nt)
        #pragma unroll
        for (int r = 0; r < 4; ++r)
          out8[mt][nt][r] = fmaf(wo, fmaxf(acc2[mt][nt][r] + bb[r], 0.0f), out8[mt][nt][r]);
    }
  }

  // ---- states write-back (direct, 16B per store) ----
  #pragma unroll
  for (int nt = 0; nt < 2; ++nt) {
    if (act[nt]) {
      float* wr = states + (size_t)tok[nt] * HD;
      #pragma unroll
      for (int mt = 0; mt < 4; ++mt) {
        float4 v; v.x = out8[mt][nt][0]; v.y = out8[mt][nt][1];
        v.z = out8[mt][nt][2]; v.w = out8[mt][nt][3];
        *(float4*)(wr + 16 * mt + 4 * g) = v;
      }
    }
  }

  if (!hc.last_hop) {
    // ---- routing: r1 = relu(out @ rW1 + rb1) ----
    store8_raw(out8, ws, lane);
    short8v bo[3][2][2];
    load_bf2(ws, lane, bo);
    f32x4 accr[4][2] = {{zf, zf}, {zf, zf}, {zf, zf}, {zf, zf}};
    mfma_allB(rw1f, bo, lane, accr);
    store8_rb(accr, rb1, ws, lane);
    short8v br[3][2][2];
    load_bf2(ws, lane, br);

    // ---- logits = r1 @ rW2 (16-cat m-tile, both n-tiles) ----
    f32x4 lg[2] = {zf, zf};
    #pragma unroll
    for (int sw = 0; sw < 3; ++sw) {
      short8v a2[2];
      #pragma unroll
      for (int kc = 0; kc < 2; ++kc)
        a2[kc] = *(const short8v*)(rw2f + (size_t)(sw * 2 + kc) * 512 + lane * 8);
      #pragma unroll
      for (int sa = 0; sa < 3; ++sa) {
        if (sw + sa > 2) continue;
        #pragma unroll
        for (int nt = 0; nt < 2; ++nt)
          #pragma unroll
          for (int kc = 0; kc < 2; ++kc)
            lg[nt] = __builtin_amdgcn_mfma_f32_16x16x32_bf16(a2[kc], br[sa][nt][kc],
                                                             lg[nt], 0, 0, 0);
      }
    }

    // ---- gumbel-argmax: lane handles cats 4g..4g+3 of its tokens ----
    #pragma unroll
    for (int nt = 0; nt < 2; ++nt) {
      float best = -3.0e38f; int bc = 0;
      const unsigned jbase = (unsigned)tok[nt] * (unsigned)NCAT;
      #pragma unroll
      for (int r = 0; r < 4; ++r) {
        const int c = 4 * g + r;
        if (c < NCAT) {
          const unsigned bits = tf_bits32(hc.ck0, hc.ck1, jbase + (unsigned)c);
          const float u = __uint_as_float((bits >> 9) | 0x3f800000u) - 1.0f;
          float val = u + 1.17549435e-38f;
          val = fmaxf(val, 1.17549435e-38f);
          const float gum = -logf(-logf(val));
          const float sc = lg[nt][r] + rb2[c] + gum;
          if (sc > best) { best = sc; bc = c; }
        }
      }
      #pragma unroll
      for (int off = 16; off <= 32; off <<= 1) {
        const float ob = __shfl_xor(best, off, 64);
        const int oc = __shfl_xor(bc, off, 64);
        if (ob > best || (ob == best && oc < bc)) { best = ob; bc = oc; }
      }
      if (g == 0 && act[nt]) {
        const int ntp = bc < (TN - 1) ? bc : (TN - 1);
        tempers[tok[nt]] = ntp;
        if (bc == TN) done[tok[nt]] = 1;
        else atomicAdd(&lcnt[ntp], 1);
      }
    }
    __syncthreads();
    if (tid < TN && lcnt[tid] > 0) atomicAdd(&cnt_next[tid], lcnt[tid]);
  }
}

// pred = states @ pred_W + pred_b via bf16x3 MFMA; fused err reduction
__global__ __launch_bounds__(512, 4) void k_pred(
    const float* __restrict__ states, const float* __restrict__ x,
    const unsigned short* __restrict__ pwf, const float* __restrict__ pdb,
    float* __restrict__ pred, float* __restrict__ err)
{
  __shared__ unsigned short sX[3 * 64 * 64];   // 24KB states splits
  __shared__ float sP[64 * 128];               // 32KB pred
  const int tid = threadIdx.x;
  const int lane = tid & 63;
  const int w = __builtin_amdgcn_readfirstlane(tid >> 6);
  const int mgrp = w & 3, ngrp = w >> 2;       // 4 d-quarters x 2 tok-halves
  const int bstart = blockIdx.x * 64;

  // stage states (coalesced): thread = (tok=tid>>3, c0=tid&7), 8 h each
  {
    const int tok = tid >> 3, c0 = tid & 7;
    const float* sr = states + (size_t)(bstart + tok) * HD + c0 * 8;
    float v[8];
    #pragma unroll
    for (int q = 0; q < 2; ++q) {
      const float4 f = *(const float4*)(sr + q * 4);
      v[q*4] = f.x; v[q*4+1] = f.y; v[q*4+2] = f.z; v[q*4+3] = f.w;
    }
    unsigned short sp[3][8];
    #pragma unroll
    for (int i = 0; i < 8; ++i) split3(v[i], sp[0][i], sp[1][i], sp[2][i]);
    const int chunk = c0 ^ (tok & 7);
    #pragma unroll
    for (int s = 0; s < 3; ++s) {
      ushort8v u;
      #pragma unroll
      for (int i = 0; i < 8; ++i) u[i] = sp[s][i];
      *(ushort8v*)(sX + s * 4096 + tok * 64 + chunk * 8) = u;
    }
  }
  __syncthreads();

  const f32x4 zf = {0.0f, 0.0f, 0.0f, 0.0f};
  short8v bf[3][2][2];
  #pragma unroll
  for (int s = 0; s < 3; ++s)
    #pragma unroll
    for (int nt = 0; nt < 2; ++nt)
      #pragma unroll
      for (int kc = 0; kc < 2; ++kc) {
        const int tk = (lane & 15) + 16 * (2 * ngrp + nt);
        const int chunk = (4 * kc + (lane >> 4)) ^ (tk & 7);
        bf[s][nt][kc] = *(const short8v*)(sX + s * 4096 + tk * 64 + chunk * 8);
      }

  f32x4 acc[2][2] = {{zf, zf}, {zf, zf}};
  #pragma unroll
  for (int sw = 0; sw < 3; ++sw) {
    short8v a[2][2];
    #pragma unroll
    for (int mt = 0; mt < 2; ++mt)
      #pragma unroll
      for (int kc = 0; kc < 2; ++kc)
        a[mt][kc] = *(const short8v*)(pwf +
            (size_t)((sw * 8 + (2 * mgrp + mt)) * 2 + kc) * 512 + lane * 8);
    #pragma unroll
    for (int sa = 0; sa < 3; ++sa) {
      if (sw + sa > 2) continue;
      #pragma unroll
      for (int mt = 0; mt < 2; ++mt)
        #pragma unroll
        for (int nt = 0; nt < 2; ++nt)
          #pragma unroll
          for (int kc = 0; kc < 2; ++kc)
            acc[mt][nt] = __builtin_amdgcn_mfma_f32_16x16x32_bf16(
                a[mt][kc], bf[sa][nt][kc], acc[mt][nt], 0, 0, 0);
    }
  }

  // D + bias -> swizzled f32 LDS
  #pragma unroll
  for (int mt = 0; mt < 2; ++mt) {
    const int mt2 = 2 * mgrp + mt;
    const int d0 = 16 * mt2 + 4 * (lane >> 4);
    const float4 bv = *(const float4*)(pdb + d0);
    const float bb[4] = {bv.x, bv.y, bv.z, bv.w};
    #pragma unroll
    for (int nt = 0; nt < 2; ++nt) {
      const int tok = (lane & 15) + 16 * (2 * ngrp + nt);
      f32x4 vv;
      #pragma unroll
      for (int r = 0; r < 4; ++r) vv[r] = acc[mt][nt][r] + bb[r];
      const int chunk = (d0 >> 2) ^ (tok & 7);
      *(f32x4*)(sP + tok * 128 + chunk * 4) = vv;
    }
  }
  __syncthreads();

  // coalesced pred write + fused err
  {
    const int tok = tid >> 3, c0 = tid & 7;
    const int n = bstart + tok;
    const float* xr = x + (size_t)n * DIN;
    float* pr = pred + (size_t)n * DIN;
    float s = 0.0f;
    #pragma unroll
    for (int q = 0; q < 4; ++q) {
      const int c = c0 + 8 * q;
      const int cs = c ^ (tok & 7);
      const f32x4 pv = *(const f32x4*)(sP + tok * 128 + cs * 4);
      const float4 xv = *(const float4*)(xr + c * 4);
      float4 ov; ov.x = pv[0]; ov.y = pv[1]; ov.z = pv[2]; ov.w = pv[3];
      *(float4*)(pr + c * 4) = ov;
      const float e0 = pv[0] - xv.x, e1 = pv[1] - xv.y, e2 = pv[2] - xv.z, e3 = pv[3] - xv.w;
      s += e0 * e0 + e1 * e1 + e2 * e2 + e3 * e3;
    }
    s += __shfl_xor(s, 1, 64);
    s += __shfl_xor(s, 2, 64);
    s += __shfl_xor(s, 4, 64);
    if (c0 == 0) err[n] = s * (1.0f / 128.0f);
  }
}

// ---- host-side RNG constant derivation ----
static float host_erfinv(float xf) {
  double x = xf;
  double w = -log1p(-x * x);
  double p;
  if (w < 5.0) {
    w -= 2.5;
    p = 2.81022636e-08;          p = 3.43273939e-07 + p * w;
    p = -3.5233877e-06 + p * w;  p = -4.39150654e-06 + p * w;
    p = 0.00021858087 + p * w;   p = -0.00125372503 + p * w;
    p = -0.00417768164 + p * w;  p = 0.246640727 + p * w;
    p = 1.50140941 + p * w;
  } else {
    w = sqrt(w) - 3.0;
    p = -0.000200214257;         p = 0.000100950558 + p * w;
    p = 0.00134934322 + p * w;   p = -0.00367342844 + p * w;
    p = 0.00573950773 + p * w;   p = -0.0076224613 + p * w;
    p = 0.00943887047 + p * w;   p = 1.00167406 + p * w;
    p = 2.83297682 + p * w;
  }
  return (float)(p * x);
}

static void build_hops(HopConst* hcs) {
  const float lo = nextafterf(-1.0f, 0.0f);
  const unsigned rk0 = 0u, rk1 = 42u;
  for (int hop = 0; hop < NHOPS; ++hop) {
    unsigned hk0, hk1;
    tf2x32(rk0, rk1, 0u, (unsigned)hop, hk0, hk1);
    for (int t = 0; t < TN; ++t) {
      unsigned tk0, tk1;
      tf2x32(hk0, hk1, 0u, (unsigned)t, tk0, tk1);
      double nrm[3];
      for (int i = 0; i < 3; ++i) {
        const unsigned bits = tf_bits32(tk0, tk1, (unsigned)i);
        unsigned ub = (bits >> 9) | 0x3f800000u;
        float f; memcpy(&f, &ub, 4);
        const float u01 = f - 1.0f;
        float val = u01 * 2.0f + lo;
        if (val < lo) val = lo;
        const float ef = host_erfinv(val);
        nrm[i] = (double)(1.41421356f * ef);
      }
      const double m = fmax(nrm[0], fmax(nrm[1], nrm[2]));
      const double e0 = exp(nrm[0] - m), e1 = exp(nrm[1] - m), e2 = exp(nrm[2] - m);
      const double s = e0 + e1 + e2;
      hcs[hop].w[t][0] = (float)(e0 / s);
      hcs[hop].w[t][1] = (float)(e1 / s);
      hcs[hop].w[t][2] = (float)(e2 / s);
    }
    unsigned ck0, ck1;
    tf2x32(hk0, hk1, 0u, 10000u, ck0, ck1);
    hcs[hop].ck0 = ck0; hcs[hop].ck1 = ck1;
    hcs[hop].last_hop = (hop == NHOPS - 1) ? 1 : 0;
  }
}

extern "C" void kernel_launch(void* const* d_in, const int* in_sizes, int n_in,
                              void* d_out, int out_size, void* d_ws, size_t ws_size,
                              hipStream_t stream) {
  (void)in_sizes; (void)n_in; (void)out_size; (void)ws_size;
  const float* x    = (const float*)d_in[0];
  const float* pW   = (const float*)d_in[1];
  const float* pb   = (const float*)d_in[2];
  const float* W1   = (const float*)d_in[3];
  const float* b1   = (const float*)d_in[4];
  const float* W2   = (const float*)d_in[5];
  const float* b2   = (const float*)d_in[6];
  const float* rW1  = (const float*)d_in[7];
  const float* rb1  = (const float*)d_in[8];
  const float* rW2  = (const float*)d_in[9];
  const float* rb2  = (const float*)d_in[10];
  const float* pdW  = (const float*)d_in[11];
  const float* pdb  = (const float*)d_in[12];
  const int*   itmp = (const int*)d_in[13];

  // ws: [meta 1KB][tempers N][done N][compact N+TN*TOKB][states N*64 f32]
  //     [w1f][w2f][rw1f][rw2f][pjf][pwf] (u16 frag arrays)
  int* meta    = (int*)d_ws;
  int* tempers = (int*)((char*)d_ws + 1024);
  int* done    = tempers + N_TOK;
  int* compact = done + N_TOK;
  float* states = (float*)(compact + N_TOK + TN * TOKB);
  unsigned short* w1f  = (unsigned short*)(states + (size_t)N_TOK * HD);
  unsigned short* w2f  = w1f + (size_t)TN * ON * 12288;
  unsigned short* rw1f = w2f + (size_t)TN * ON * 12288;
  unsigned short* rw2f = rw1f + 12288;
  unsigned short* pjf  = rw2f + 3072;
  unsigned short* pwf  = pjf + 24576;

  HopConst hcs[NHOPS];
  build_hops(hcs);

  hipMemsetAsync(meta, 0, 160 * sizeof(int), stream);
  k_wprep<<<83, TPB, 0, stream>>>(W1, W2, rW1, rW2, pW, pdW,
                                  w1f, w2f, rw1f, rw2f, pjf, pwf);
  k_init<<<N_TOK / 64, 512, 0, stream>>>(x, pjf, pb, itmp, states, tempers, done, meta);
  for (int h = 0; h < NHOPS; ++h) {
    int* cnt_h = meta + h * TN;
    int* cnt_n = meta + (h + 1) * TN;
    int* cur_h = meta + 60 + h * TN;
    int* off_h = meta + 108 + h * (TN + 1);
    k_prefix<<<1, 64, 0, stream>>>(cnt_h, off_h);
    k_scatter<<<N_TOK / TPB, TPB, 0, stream>>>(tempers, done, off_h, cur_h, compact);
    k_hop<<<N_TOK / TOKB + TN, TPB, 0, stream>>>(states, tempers, done, compact, cnt_h, off_h,
        w1f, b1, w2f, b2, rw1f, rb1, rw2f, rb2, cnt_n, hcs[h]);
  }
  float* pred = (float*)d_out;
  float* errp = pred + (size_t)N_TOK * DIN;
  k_pred<<<N_TOK / 64, 512, 0, stream>>>(states, x, pwf, pdb, pred, errp);
}

// Round 12
// 241.834 us; speedup vs baseline: 1.1090x; 1.1090x over previous
//
#include <hip/hip_runtime.h>
#include <cstring>
#include <cmath>
#include <cstdint>

#define N_TOK 65536
#define DIN 128
#define HD 64
#define TN 12
#define ON 3
#define NHOPS 4
#define TPB 256
#define TOKB 64          // tokens per k_hop block (4 waves x 16 tokens)
#define NCAT 13

typedef __attribute__((ext_vector_type(8))) short short8v;     // 8 bf16 frag
typedef __attribute__((ext_vector_type(4))) float f32x4;
typedef __attribute__((ext_vector_type(4))) unsigned short ushort4v;
typedef __attribute__((ext_vector_type(8))) unsigned short ushort8v;

struct HopConst {
  float w[TN][ON];
  unsigned ck0, ck1;
  int last_hop;
};

// ---- threefry2x32 (exact JAX semantics) ----
__host__ __device__ __forceinline__ void tf2x32(unsigned k0, unsigned k1,
                                                unsigned x0, unsigned x1,
                                                unsigned& o0, unsigned& o1) {
  unsigned ks2 = k0 ^ k1 ^ 0x1BD11BDAu;
  x0 += k0; x1 += k1;
#define TFR(r) { x0 += x1; x1 = (x1 << (r)) | (x1 >> (32 - (r))); x1 ^= x0; }
  TFR(13) TFR(15) TFR(26) TFR(6)
  x0 += k1;  x1 += ks2 + 1u;
  TFR(17) TFR(29) TFR(16) TFR(24)
  x0 += ks2; x1 += k0 + 2u;
  TFR(13) TFR(15) TFR(26) TFR(6)
  x0 += k0;  x1 += k1 + 3u;
  TFR(17) TFR(29) TFR(16) TFR(24)
  x0 += k1;  x1 += ks2 + 4u;
  TFR(13) TFR(15) TFR(26) TFR(6)
  x0 += ks2; x1 += k0 + 5u;
#undef TFR
  o0 = x0; o1 = x1;
}
__host__ __device__ __forceinline__ unsigned tf_bits32(unsigned k0, unsigned k1, unsigned j) {
  unsigned o0, o1;
  tf2x32(k0, k1, 0u, j, o0, o1);
  return o0 ^ o1;
}

// ---- bf16x3 splitting ----
__host__ __device__ __forceinline__ unsigned short bf16r(float v) {
  unsigned u = __builtin_bit_cast(unsigned, v);
  return (unsigned short)((u + 0x7fffu + ((u >> 16) & 1u)) >> 16);
}
__host__ __device__ __forceinline__ float bf2f(unsigned short s) {
  return __builtin_bit_cast(float, ((unsigned)s) << 16);
}
__host__ __device__ __forceinline__ void split3(float v, unsigned short& a,
                                                unsigned short& b, unsigned short& c) {
  a = bf16r(v); float r = v - bf2f(a);
  b = bf16r(r); r -= bf2f(b);
  c = bf16r(r);
}

// ---- kernels ----

// init: states = x @ proj_W + proj_b via bf16x3 MFMA; tempers/done/histogram
__global__ __launch_bounds__(512, 4) void k_init(
    const float* __restrict__ x, const unsigned short* __restrict__ pjf,
    const float* __restrict__ pb, const int* __restrict__ itemp,
    float* __restrict__ states, int* __restrict__ tempers,
    int* __restrict__ done, int* __restrict__ cnt0)
{
  __shared__ unsigned short sX[3 * 64 * 128];  // 48KB x splits
  __shared__ float sOut[64 * 64];              // 16KB out
  __shared__ int lcnt[TN];
  const int tid = threadIdx.x;
  const int lane = tid & 63;
  const int w = __builtin_amdgcn_readfirstlane(tid >> 6);
  const int mgrp = w & 1, ngrp = w >> 1;       // 2 feat-halves x 4 tok-quarters
  const int bstart = blockIdx.x * 64;

  // stage x (coalesced): thread = (tok=tid>>3, c0=tid&7), 16 k each
  {
    const int tok = tid >> 3, c0 = tid & 7;
    const float* xr = x + (size_t)(bstart + tok) * DIN + c0 * 16;
    float v[16];
    #pragma unroll
    for (int q = 0; q < 4; ++q) {
      const float4 f = *(const float4*)(xr + q * 4);
      v[q*4] = f.x; v[q*4+1] = f.y; v[q*4+2] = f.z; v[q*4+3] = f.w;
    }
    unsigned short sp[3][16];
    #pragma unroll
    for (int i = 0; i < 16; ++i) split3(v[i], sp[0][i], sp[1][i], sp[2][i]);
    #pragma unroll
    for (int s = 0; s < 3; ++s)
      #pragma unroll
      for (int jj = 0; jj < 2; ++jj) {
        ushort8v u;
        #pragma unroll
        for (int i = 0; i < 8; ++i) u[i] = sp[s][jj * 8 + i];
        const int chunk = (2 * c0 + jj) ^ (tok & 7);
        *(ushort8v*)(sX + s * 8192 + tok * 128 + chunk * 8) = u;
      }
  }
  if (tid < TN) lcnt[tid] = 0;
  __syncthreads();

  const f32x4 zf = {0.0f, 0.0f, 0.0f, 0.0f};
  const int tok16 = (lane & 15) + 16 * ngrp;
  short8v bf[3][4];
  #pragma unroll
  for (int s = 0; s < 3; ++s)
    #pragma unroll
    for (int kc = 0; kc < 4; ++kc) {
      const int chunk = (4 * kc + (lane >> 4)) ^ (tok16 & 7);
      bf[s][kc] = *(const short8v*)(sX + s * 8192 + tok16 * 128 + chunk * 8);
    }
  f32x4 acc[2] = {zf, zf};
  #pragma unroll
  for (int sw = 0; sw < 3; ++sw) {
    short8v a[2][4];
    #pragma unroll
    for (int mt = 0; mt < 2; ++mt)
      #pragma unroll
      for (int kc = 0; kc < 4; ++kc)
        a[mt][kc] = *(const short8v*)(pjf +
            (size_t)((sw * 4 + (2 * mgrp + mt)) * 4 + kc) * 512 + lane * 8);
    #pragma unroll
    for (int sa = 0; sa < 3; ++sa) {
      if (sw + sa > 2) continue;
      #pragma unroll
      for (int mt = 0; mt < 2; ++mt)
        #pragma unroll
        for (int kc = 0; kc < 4; ++kc)
          acc[mt] = __builtin_amdgcn_mfma_f32_16x16x32_bf16(
              a[mt][kc], bf[sa][kc], acc[mt], 0, 0, 0);
    }
  }

  // D + bias -> swizzled f32 LDS
  #pragma unroll
  for (int mt = 0; mt < 2; ++mt) {
    const int mt2 = 2 * mgrp + mt;
    const int j0 = 16 * mt2 + 4 * (lane >> 4);
    const float4 bv = *(const float4*)(pb + j0);
    const float bb[4] = {bv.x, bv.y, bv.z, bv.w};
    f32x4 vv;
    #pragma unroll
    for (int r = 0; r < 4; ++r) vv[r] = acc[mt][r] + bb[r];
    const int chunk = (4 * mt2 + (lane >> 4)) ^ (tok16 & 15);
    *(f32x4*)(sOut + tok16 * 64 + chunk * 4) = vv;
  }
  __syncthreads();

  // coalesced states write-back
  {
    const int tok = tid >> 3, c0 = tid & 7;
    const int n = bstart + tok;
    float* wr = states + (size_t)n * HD;
    #pragma unroll
    for (int q = 0; q < 2; ++q) {
      const int c = c0 + 8 * q;
      const int cs = c ^ (tok & 15);
      *(float4*)(wr + c * 4) = *(const float4*)(sOut + tok * 64 + cs * 4);
    }
  }
  if (tid < 64) {
    const int n = bstart + tid;
    const int t = itemp[n];
    tempers[n] = t;
    done[n] = 0;
    atomicAdd(&lcnt[t], 1);
  }
  __syncthreads();
  if (tid < TN && lcnt[tid] > 0) atomicAdd(&cnt0[tid], lcnt[tid]);
}

// one-time: split weights to bf16x3 in MFMA A-frag order.
// A-frag: frag(s, mtile, kc, lane) holds A[m=16*mtile+(lane&15)][k=32*kc+8*(lane>>4)+i]
__global__ __launch_bounds__(TPB) void k_wprep(
    const float* __restrict__ W1, const float* __restrict__ W2,
    const float* __restrict__ rW1, const float* __restrict__ rW2,
    const float* __restrict__ pjW, const float* __restrict__ pdW,
    unsigned short* __restrict__ w1f, unsigned short* __restrict__ w2f,
    unsigned short* __restrict__ rw1f, unsigned short* __restrict__ rw2f,
    unsigned short* __restrict__ pjf, unsigned short* __restrict__ pwf)
{
  const int idx = blockIdx.x * TPB + threadIdx.x;
  const int NU1 = TN * ON * 4 * 2 * 64;   // 18432
  const int NU2 = 4 * 2 * 64;             // 512
  const int NU3 = 2 * 64;                 // 128
  const int NU4 = 4 * 4 * 64;             // 1024 proj_W (4 mt x 4 kc)
  const int NU5 = 8 * 2 * 64;             // 1024 pred_W (8 mt x 2 kc)
  if (idx < NU1) {
    const int lane = idx & 63, kc = (idx >> 6) & 1, mt = (idx >> 7) & 3, mat = idx >> 9;
    const int j = 16 * mt + (lane & 15);
    const int h0 = 32 * kc + 8 * (lane >> 4);
    const float* s1 = W1 + (size_t)mat * 4096;
    const float* s2 = W2 + (size_t)mat * 4096;
    #pragma unroll
    for (int i = 0; i < 8; ++i) {
      unsigned short a0, a1, a2;
      const size_t base = (size_t)mat * 12288 + (size_t)(mt * 2 + kc) * 512 + lane * 8 + i;
      split3(s1[(h0 + i) * 64 + j], a0, a1, a2);
      w1f[base] = a0; w1f[base + 4096] = a1; w1f[base + 8192] = a2;
      split3(s2[(h0 + i) * 64 + j], a0, a1, a2);
      w2f[base] = a0; w2f[base + 4096] = a1; w2f[base + 8192] = a2;
    }
  } else if (idx < NU1 + NU2) {
    const int u = idx - NU1;
    const int lane = u & 63, kc = (u >> 6) & 1, mt = (u >> 7) & 3;
    const int j = 16 * mt + (lane & 15);
    const int h0 = 32 * kc + 8 * (lane >> 4);
    #pragma unroll
    for (int i = 0; i < 8; ++i) {
      unsigned short a0, a1, a2;
      const size_t base = (size_t)(mt * 2 + kc) * 512 + lane * 8 + i;
      split3(rW1[(h0 + i) * 64 + j], a0, a1, a2);
      rw1f[base] = a0; rw1f[base + 4096] = a1; rw1f[base + 8192] = a2;
    }
  } else if (idx < NU1 + NU2 + NU3) {
    const int u = idx - NU1 - NU2;
    const int lane = u & 63, kc = (u >> 6) & 1;
    const int c = lane & 15;
    const int h0 = 32 * kc + 8 * (lane >> 4);
    #pragma unroll
    for (int i = 0; i < 8; ++i) {
      unsigned short a0, a1, a2;
      const float v = (c < NCAT) ? rW2[(h0 + i) * NCAT + c] : 0.0f;
      split3(v, a0, a1, a2);
      const size_t base = (size_t)kc * 512 + lane * 8 + i;
      rw2f[base] = a0; rw2f[base + 1024] = a1; rw2f[base + 2048] = a2;
    }
  } else if (idx < NU1 + NU2 + NU3 + NU4) {
    const int u = idx - (NU1 + NU2 + NU3);
    const int lane = u & 63, kc = (u >> 6) & 3, mt = u >> 8;
    const int j = 16 * mt + (lane & 15);
    const int k0 = 32 * kc + 8 * (lane >> 4);
    #pragma unroll
    for (int i = 0; i < 8; ++i) {
      unsigned short a0, a1, a2;
      split3(pjW[(size_t)(k0 + i) * 64 + j], a0, a1, a2);
      const size_t base = (size_t)(mt * 4 + kc) * 512 + lane * 8 + i;
      pjf[base] = a0; pjf[base + 8192] = a1; pjf[base + 16384] = a2;
    }
  } else if (idx < NU1 + NU2 + NU3 + NU4 + NU5) {
    const int u = idx - (NU1 + NU2 + NU3 + NU4);
    const int lane = u & 63, kc = (u >> 6) & 1, mt = u >> 7;
    const int d = 16 * mt + (lane & 15);
    const int h0 = 32 * kc + 8 * (lane >> 4);
    #pragma unroll
    for (int i = 0; i < 8; ++i) {
      unsigned short a0, a1, a2;
      split3(pdW[(size_t)(h0 + i) * 128 + d], a0, a1, a2);
      const size_t base = (size_t)(mt * 2 + kc) * 512 + lane * 8 + i;
      pwf[base] = a0; pwf[base + 8192] = a1; pwf[base + 16384] = a2;
    }
  }
}

__global__ void k_prefix(const int* __restrict__ cnt, int* __restrict__ offp) {
  if (threadIdx.x == 0 && blockIdx.x == 0) {
    int o = 0;
    for (int t = 0; t < TN; ++t) { offp[t] = o; o += (cnt[t] + TOKB - 1) & ~(TOKB - 1); }
    offp[TN] = o;
  }
}

__global__ __launch_bounds__(TPB) void k_scatter(
    const int* __restrict__ tempers, const int* __restrict__ done,
    const int* __restrict__ offp, int* __restrict__ cursor, int* __restrict__ compact)
{
  __shared__ int lcnt[TN], lbase[TN];
  const int tid = threadIdx.x;
  if (tid < TN) lcnt[tid] = 0;
  __syncthreads();
  const int n = blockIdx.x * TPB + tid;
  int t = -1, lpos = 0;
  if (!done[n]) { t = tempers[n]; lpos = atomicAdd(&lcnt[t], 1); }
  __syncthreads();
  if (tid < TN && lcnt[tid] > 0) lbase[tid] = atomicAdd(&cursor[tid], lcnt[tid]);
  __syncthreads();
  if (t >= 0) compact[offp[t] + lbase[t] + lpos] = n;
}

// ---- wave-local helpers (16 tokens x 64 features per wave) ----

// scratch layout per split s: idx = n*64 + ((f>>3)^(n&7))*8 + (f&7)  (u16 units)
__device__ __forceinline__ void load_bf(const unsigned short* src, int lane, short8v bf[3][2]) {
  const int n = lane & 15, g = lane >> 4;
  #pragma unroll
  for (int s = 0; s < 3; ++s)
    #pragma unroll
    for (int kc = 0; kc < 2; ++kc) {
      const int chunk = (4 * kc + g) ^ (n & 7);
      bf[s][kc] = *(const short8v*)(src + s * 1024 + n * 64 + chunk * 8);
    }
}

// 6-pass bf16x3 MFMA, 4 m-tiles x 16 tokens, depth-1 software pipeline:
// prefetch sw+1's 8 A-frags while sw's MFMA burst runs. MFMA order per
// accumulator identical to R10 -> bit-identical results.
__device__ __forceinline__ void mfma_all4(const unsigned short* __restrict__ Ag,
                                          const short8v bf[3][2], int lane, f32x4 acc[4]) {
  short8v acur[8], anxt[8];
  #pragma unroll
  for (int u = 0; u < 8; ++u)
    acur[u] = *(const short8v*)(Ag + (size_t)u * 512 + lane * 8);
  #pragma unroll
  for (int sw = 0; sw < 3; ++sw) {
    if (sw < 2) {
      #pragma unroll
      for (int u = 0; u < 8; ++u)
        anxt[u] = *(const short8v*)(Ag + (size_t)((sw + 1) * 8 + u) * 512 + lane * 8);
    }
    #pragma unroll
    for (int sa = 0; sa < 3; ++sa) {
      if (sw + sa > 2) continue;
      #pragma unroll
      for (int mt = 0; mt < 4; ++mt)
        #pragma unroll
        for (int kc = 0; kc < 2; ++kc)
          acc[mt] = __builtin_amdgcn_mfma_f32_16x16x32_bf16(
              acur[mt * 2 + kc], bf[sa][kc], acc[mt], 0, 0, 0);
    }
    if (sw < 2) {
      #pragma unroll
      for (int u = 0; u < 8; ++u) acur[u] = anxt[u];
    }
  }
}

// bias + relu + split3 -> wave-local swizzled scratch
__device__ __forceinline__ void store4_rb(const f32x4 acc[4], const float* __restrict__ bias,
                                          unsigned short* dst, int lane) {
  const int n = lane & 15, g = lane >> 4;
  #pragma unroll
  for (int mt = 0; mt < 4; ++mt) {
    const int j0 = 16 * mt + 4 * g;
    const float4 bv = *(const float4*)(bias + j0);
    const float bb[4] = {bv.x, bv.y, bv.z, bv.w};
    ushort4v u0, u1, u2;
    #pragma unroll
    for (int r = 0; r < 4; ++r) {
      const float v = fmaxf(acc[mt][r] + bb[r], 0.0f);
      unsigned short a, b, c;
      split3(v, a, b, c);
      u0[r] = a; u1[r] = b; u2[r] = c;
    }
    const int idx = n * 64 + ((2 * mt + (g >> 1)) ^ (n & 7)) * 8 + 4 * (g & 1);
    *(ushort4v*)(dst + idx) = u0;
    *(ushort4v*)(dst + 1024 + idx) = u1;
    *(ushort4v*)(dst + 2048 + idx) = u2;
  }
}

// raw split3 -> scratch (no bias/relu) for routing input
__device__ __forceinline__ void store4_raw(const f32x4 acc[4], unsigned short* dst, int lane) {
  const int n = lane & 15, g = lane >> 4;
  #pragma unroll
  for (int mt = 0; mt < 4; ++mt) {
    ushort4v u0, u1, u2;
    #pragma unroll
    for (int r = 0; r < 4; ++r) {
      unsigned short a, b, c;
      split3(acc[mt][r], a, b, c);
      u0[r] = a; u1[r] = b; u2[r] = c;
    }
    const int idx = n * 64 + ((2 * mt + (g >> 1)) ^ (n & 7)) * 8 + 4 * (g & 1);
    *(ushort4v*)(dst + idx) = u0;
    *(ushort4v*)(dst + 1024 + idx) = u1;
    *(ushort4v*)(dst + 2048 + idx) = u2;
  }
}

// main per-hop kernel: barrier-free per-wave pipeline. Each wave owns 16
// tokens x all 64 features; exchange via private 6KB LDS scratch (lgkmcnt
// only, no __syncthreads). launch_bounds(256,2): ~128 VGPR so the A-frag
// prefetch pipeline fits in registers.
__global__ __launch_bounds__(TPB, 2) void k_hop(
    float* __restrict__ states, int* __restrict__ tempers, int* __restrict__ done,
    const int* __restrict__ compact, const int* __restrict__ cnt,
    const int* __restrict__ offp,
    const unsigned short* __restrict__ w1f, const float* __restrict__ b1,
    const unsigned short* __restrict__ w2f, const float* __restrict__ b2,
    const unsigned short* __restrict__ rw1f, const float* __restrict__ rb1,
    const unsigned short* __restrict__ rw2f, const float* __restrict__ rb2,
    int* __restrict__ cnt_next, HopConst hc)
{
  __shared__ unsigned short scr[4][3072];   // 24KB: 6KB private scratch per wave
  __shared__ int lcnt[TN];

  const int tid = threadIdx.x;
  const int lane = tid & 63;
  const int wid = __builtin_amdgcn_readfirstlane(tid >> 6);
  unsigned short* ws = scr[wid];
  const int bstart = blockIdx.x * TOKB;
  if (bstart >= offp[TN]) return;
  if (tid < TN) lcnt[tid] = 0;
  int tt = 0;
  #pragma unroll
  for (int i = 1; i < TN; ++i) if (bstart >= offp[i]) tt = i;
  const int t = __builtin_amdgcn_readfirstlane(tt);
  const int cntt = cnt[t];
  const int n = lane & 15, g = lane >> 4;
  const int pos = bstart + wid * 16 + n;
  const bool act = (pos - offp[t]) < cntt;
  const int tok = compact[act ? pos : offp[t]];

  // ---- stage states in-register: lane loads its token's k-slices ----
  short8v bx[3][2];
  {
    const float* sr = states + (size_t)tok * HD;
    float va[8], vb[8];
    #pragma unroll
    for (int q = 0; q < 2; ++q) {
      const float4 f0 = *(const float4*)(sr + 8 * g + q * 4);
      const float4 f1 = *(const float4*)(sr + 32 + 8 * g + q * 4);
      va[q*4] = f0.x; va[q*4+1] = f0.y; va[q*4+2] = f0.z; va[q*4+3] = f0.w;
      vb[q*4] = f1.x; vb[q*4+1] = f1.y; vb[q*4+2] = f1.z; vb[q*4+3] = f1.w;
    }
    unsigned short sa_[3][8], sb_[3][8];
    #pragma unroll
    for (int i = 0; i < 8; ++i) {
      split3(va[i], sa_[0][i], sa_[1][i], sa_[2][i]);
      split3(vb[i], sb_[0][i], sb_[1][i], sb_[2][i]);
    }
    #pragma unroll
    for (int s = 0; s < 3; ++s) {
      short8v u0, u1;
      #pragma unroll
      for (int i = 0; i < 8; ++i) { u0[i] = (short)sa_[s][i]; u1[i] = (short)sb_[s][i]; }
      bx[s][0] = u0; bx[s][1] = u1;
    }
  }
  __syncthreads();   // lcnt init visible before any sampling adds

  const f32x4 zf = {0.0f, 0.0f, 0.0f, 0.0f};
  f32x4 out4[4] = {zf, zf, zf, zf};

  #pragma unroll 1
  for (int o = 0; o < ON; ++o) {
    const int mat = t * ON + o;
    f32x4 acc[4] = {zf, zf, zf, zf};
    mfma_all4(w1f + (size_t)mat * 12288, bx, lane, acc);
    store4_rb(acc, b1 + mat * 64, ws, lane);          // h1 splits -> wave scratch
    short8v bh[3][2];
    load_bf(ws, lane, bh);                            // lgkmcnt-ordered, wave-local
    f32x4 acc2[4] = {zf, zf, zf, zf};
    mfma_all4(w2f + (size_t)mat * 12288, bh, lane, acc2);
    const float wo = hc.w[t][o];
    #pragma unroll
    for (int mt = 0; mt < 4; ++mt) {
      const float4 bv = *(const float4*)(b2 + mat * 64 + 16 * mt + 4 * g);
      const float bb[4] = {bv.x, bv.y, bv.z, bv.w};
      #pragma unroll
      for (int r = 0; r < 4; ++r)
        out4[mt][r] = fmaf(wo, fmaxf(acc2[mt][r] + bb[r], 0.0f), out4[mt][r]);
    }
  }

  // ---- states write-back (direct, 16B per store) ----
  if (act) {
    float* wr = states + (size_t)tok * HD;
    #pragma unroll
    for (int mt = 0; mt < 4; ++mt) {
      float4 v; v.x = out4[mt][0]; v.y = out4[mt][1]; v.z = out4[mt][2]; v.w = out4[mt][3];
      *(float4*)(wr + 16 * mt + 4 * g) = v;
    }
  }

  if (!hc.last_hop) {
    // ---- routing: r1 = relu(out @ rW1 + rb1) ----
    store4_raw(out4, ws, lane);
    short8v bo[3][2];
    load_bf(ws, lane, bo);
    f32x4 accr[4] = {zf, zf, zf, zf};
    mfma_all4(rw1f, bo, lane, accr);
    store4_rb(accr, rb1, ws, lane);
    short8v br[3][2];
    load_bf(ws, lane, br);

    // ---- logits = r1 @ rW2 (1 m-tile of 16 cats) ----
    f32x4 lg = zf;
    #pragma unroll
    for (int sw = 0; sw < 3; ++sw) {
      short8v a2[2];
      #pragma unroll
      for (int kc = 0; kc < 2; ++kc)
        a2[kc] = *(const short8v*)(rw2f + (size_t)(sw * 2 + kc) * 512 + lane * 8);
      #pragma unroll
      for (int sa = 0; sa < 3; ++sa) {
        if (sw + sa > 2) continue;
        #pragma unroll
        for (int kc = 0; kc < 2; ++kc)
          lg = __builtin_amdgcn_mfma_f32_16x16x32_bf16(a2[kc], br[sa][kc], lg, 0, 0, 0);
      }
    }

    // ---- gumbel-argmax: lane handles cats 4g..4g+3 of its token ----
    float best = -3.0e38f; int bc = 0;
    const unsigned jbase = (unsigned)tok * (unsigned)NCAT;
    #pragma unroll
    for (int r = 0; r < 4; ++r) {
      const int c = 4 * g + r;
      if (c < NCAT) {
        const unsigned bits = tf_bits32(hc.ck0, hc.ck1, jbase + (unsigned)c);
        const float u = __uint_as_float((bits >> 9) | 0x3f800000u) - 1.0f;
        float val = u + 1.17549435e-38f;
        val = fmaxf(val, 1.17549435e-38f);
        const float gum = -logf(-logf(val));
        const float sc = lg[r] + rb2[c] + gum;
        if (sc > best) { best = sc; bc = c; }
      }
    }
    #pragma unroll
    for (int off = 16; off <= 32; off <<= 1) {
      const float ob = __shfl_xor(best, off, 64);
      const int oc = __shfl_xor(bc, off, 64);
      if (ob > best || (ob == best && oc < bc)) { best = ob; bc = oc; }
    }
    if (g == 0 && act) {
      const int nt = bc < (TN - 1) ? bc : (TN - 1);
      tempers[tok] = nt;
      if (bc == TN) done[tok] = 1;
      else atomicAdd(&lcnt[nt], 1);
    }
    __syncthreads();
    if (tid < TN && lcnt[tid] > 0) atomicAdd(&cnt_next[tid], lcnt[tid]);
  }
}

// pred = states @ pred_W + pred_b via bf16x3 MFMA; fused err reduction
__global__ __launch_bounds__(512, 4) void k_pred(
    const float* __restrict__ states, const float* __restrict__ x,
    const unsigned short* __restrict__ pwf, const float* __restrict__ pdb,
    float* __restrict__ pred, float* __restrict__ err)
{
  __shared__ unsigned short sX[3 * 64 * 64];   // 24KB states splits
  __shared__ float sP[64 * 128];               // 32KB pred
  const int tid = threadIdx.x;
  const int lane = tid & 63;
  const int w = __builtin_amdgcn_readfirstlane(tid >> 6);
  const int mgrp = w & 3, ngrp = w >> 2;       // 4 d-quarters x 2 tok-halves
  const int bstart = blockIdx.x * 64;

  // stage states (coalesced): thread = (tok=tid>>3, c0=tid&7), 8 h each
  {
    const int tok = tid >> 3, c0 = tid & 7;
    const float* sr = states + (size_t)(bstart + tok) * HD + c0 * 8;
    float v[8];
    #pragma unroll
    for (int q = 0; q < 2; ++q) {
      const float4 f = *(const float4*)(sr + q * 4);
      v[q*4] = f.x; v[q*4+1] = f.y; v[q*4+2] = f.z; v[q*4+3] = f.w;
    }
    unsigned short sp[3][8];
    #pragma unroll
    for (int i = 0; i < 8; ++i) split3(v[i], sp[0][i], sp[1][i], sp[2][i]);
    const int chunk = c0 ^ (tok & 7);
    #pragma unroll
    for (int s = 0; s < 3; ++s) {
      ushort8v u;
      #pragma unroll
      for (int i = 0; i < 8; ++i) u[i] = sp[s][i];
      *(ushort8v*)(sX + s * 4096 + tok * 64 + chunk * 8) = u;
    }
  }
  __syncthreads();

  const f32x4 zf = {0.0f, 0.0f, 0.0f, 0.0f};
  short8v bf[3][2][2];
  #pragma unroll
  for (int s = 0; s < 3; ++s)
    #pragma unroll
    for (int nt = 0; nt < 2; ++nt)
      #pragma unroll
      for (int kc = 0; kc < 2; ++kc) {
        const int tk = (lane & 15) + 16 * (2 * ngrp + nt);
        const int chunk = (4 * kc + (lane >> 4)) ^ (tk & 7);
        bf[s][nt][kc] = *(const short8v*)(sX + s * 4096 + tk * 64 + chunk * 8);
      }

  f32x4 acc[2][2] = {{zf, zf}, {zf, zf}};
  #pragma unroll
  for (int sw = 0; sw < 3; ++sw) {
    short8v a[2][2];
    #pragma unroll
    for (int mt = 0; mt < 2; ++mt)
      #pragma unroll
      for (int kc = 0; kc < 2; ++kc)
        a[mt][kc] = *(const short8v*)(pwf +
            (size_t)((sw * 8 + (2 * mgrp + mt)) * 2 + kc) * 512 + lane * 8);
    #pragma unroll
    for (int sa = 0; sa < 3; ++sa) {
      if (sw + sa > 2) continue;
      #pragma unroll
      for (int mt = 0; mt < 2; ++mt)
        #pragma unroll
        for (int nt = 0; nt < 2; ++nt)
          #pragma unroll
          for (int kc = 0; kc < 2; ++kc)
            acc[mt][nt] = __builtin_amdgcn_mfma_f32_16x16x32_bf16(
                a[mt][kc], bf[sa][nt][kc], acc[mt][nt], 0, 0, 0);
    }
  }

  // D + bias -> swizzled f32 LDS
  #pragma unroll
  for (int mt = 0; mt < 2; ++mt) {
    const int mt2 = 2 * mgrp + mt;
    const int d0 = 16 * mt2 + 4 * (lane >> 4);
    const float4 bv = *(const float4*)(pdb + d0);
    const float bb[4] = {bv.x, bv.y, bv.z, bv.w};
    #pragma unroll
    for (int nt = 0; nt < 2; ++nt) {
      const int tok = (lane & 15) + 16 * (2 * ngrp + nt);
      f32x4 vv;
      #pragma unroll
      for (int r = 0; r < 4; ++r) vv[r] = acc[mt][nt][r] + bb[r];
      const int chunk = (d0 >> 2) ^ (tok & 7);
      *(f32x4*)(sP + tok * 128 + chunk * 4) = vv;
    }
  }
  __syncthreads();

  // coalesced pred write + fused err
  {
    const int tok = tid >> 3, c0 = tid & 7;
    const int n = bstart + tok;
    const float* xr = x + (size_t)n * DIN;
    float* pr = pred + (size_t)n * DIN;
    float s = 0.0f;
    #pragma unroll
    for (int q = 0; q < 4; ++q) {
      const int c = c0 + 8 * q;
      const int cs = c ^ (tok & 7);
      const f32x4 pv = *(const f32x4*)(sP + tok * 128 + cs * 4);
      const float4 xv = *(const float4*)(xr + c * 4);
      float4 ov; ov.x = pv[0]; ov.y = pv[1]; ov.z = pv[2]; ov.w = pv[3];
      *(float4*)(pr + c * 4) = ov;
      const float e0 = pv[0] - xv.x, e1 = pv[1] - xv.y, e2 = pv[2] - xv.z, e3 = pv[3] - xv.w;
      s += e0 * e0 + e1 * e1 + e2 * e2 + e3 * e3;
    }
    s += __shfl_xor(s, 1, 64);
    s += __shfl_xor(s, 2, 64);
    s += __shfl_xor(s, 4, 64);
    if (c0 == 0) err[n] = s * (1.0f / 128.0f);
  }
}

// ---- host-side RNG constant derivation ----
static float host_erfinv(float xf) {
  double x = xf;
  double w = -log1p(-x * x);
  double p;
  if (w < 5.0) {
    w -= 2.5;
    p = 2.81022636e-08;          p = 3.43273939e-07 + p * w;
    p = -3.5233877e-06 + p * w;  p = -4.39150654e-06 + p * w;
    p = 0.00021858087 + p * w;   p = -0.00125372503 + p * w;
    p = -0.00417768164 + p * w;  p = 0.246640727 + p * w;
    p = 1.50140941 + p * w;
  } else {
    w = sqrt(w) - 3.0;
    p = -0.000200214257;         p = 0.000100950558 + p * w;
    p = 0.00134934322 + p * w;   p = -0.00367342844 + p * w;
    p = 0.00573950773 + p * w;   p = -0.0076224613 + p * w;
    p = 0.00943887047 + p * w;   p = 1.00167406 + p * w;
    p = 2.83297682 + p * w;
  }
  return (float)(p * x);
}

static void build_hops(HopConst* hcs) {
  const float lo = nextafterf(-1.0f, 0.0f);
  const unsigned rk0 = 0u, rk1 = 42u;
  for (int hop = 0; hop < NHOPS; ++hop) {
    unsigned hk0, hk1;
    tf2x32(rk0, rk1, 0u, (unsigned)hop, hk0, hk1);
    for (int t = 0; t < TN; ++t) {
      unsigned tk0, tk1;
      tf2x32(hk0, hk1, 0u, (unsigned)t, tk0, tk1);
      double nrm[3];
      for (int i = 0; i < 3; ++i) {
        const unsigned bits = tf_bits32(tk0, tk1, (unsigned)i);
        unsigned ub = (bits >> 9) | 0x3f800000u;
        float f; memcpy(&f, &ub, 4);
        const float u01 = f - 1.0f;
        float val = u01 * 2.0f + lo;
        if (val < lo) val = lo;
        const float ef = host_erfinv(val);
        nrm[i] = (double)(1.41421356f * ef);
      }
      const double m = fmax(nrm[0], fmax(nrm[1], nrm[2]));
      const double e0 = exp(nrm[0] - m), e1 = exp(nrm[1] - m), e2 = exp(nrm[2] - m);
      const double s = e0 + e1 + e2;
      hcs[hop].w[t][0] = (float)(e0 / s);
      hcs[hop].w[t][1] = (float)(e1 / s);
      hcs[hop].w[t][2] = (float)(e2 / s);
    }
    unsigned ck0, ck1;
    tf2x32(hk0, hk1, 0u, 10000u, ck0, ck1);
    hcs[hop].ck0 = ck0; hcs[hop].ck1 = ck1;
    hcs[hop].last_hop = (hop == NHOPS - 1) ? 1 : 0;
  }
}

extern "C" void kernel_launch(void* const* d_in, const int* in_sizes, int n_in,
                              void* d_out, int out_size, void* d_ws, size_t ws_size,
                              hipStream_t stream) {
  (void)in_sizes; (void)n_in; (void)out_size; (void)ws_size;
  const float* x    = (const float*)d_in[0];
  const float* pW   = (const float*)d_in[1];
  const float* pb   = (const float*)d_in[2];
  const float* W1   = (const float*)d_in[3];
  const float* b1   = (const float*)d_in[4];
  const float* W2   = (const float*)d_in[5];
  const float* b2   = (const float*)d_in[6];
  const float* rW1  = (const float*)d_in[7];
  const float* rb1  = (const float*)d_in[8];
  const float* rW2  = (const float*)d_in[9];
  const float* rb2  = (const float*)d_in[10];
  const float* pdW  = (const float*)d_in[11];
  const float* pdb  = (const float*)d_in[12];
  const int*   itmp = (const int*)d_in[13];

  // ws: [meta 1KB][tempers N][done N][compact N+TN*TOKB][states N*64 f32]
  //     [w1f][w2f][rw1f][rw2f][pjf][pwf] (u16 frag arrays)
  int* meta    = (int*)d_ws;
  int* tempers = (int*)((char*)d_ws + 1024);
  int* done    = tempers + N_TOK;
  int* compact = done + N_TOK;
  float* states = (float*)(compact + N_TOK + TN * TOKB);
  unsigned short* w1f  = (unsigned short*)(states + (size_t)N_TOK * HD);
  unsigned short* w2f  = w1f + (size_t)TN * ON * 12288;
  unsigned short* rw1f = w2f + (size_t)TN * ON * 12288;
  unsigned short* rw2f = rw1f + 12288;
  unsigned short* pjf  = rw2f + 3072;
  unsigned short* pwf  = pjf + 24576;

  HopConst hcs[NHOPS];
  build_hops(hcs);

  hipMemsetAsync(meta, 0, 160 * sizeof(int), stream);
  k_wprep<<<83, TPB, 0, stream>>>(W1, W2, rW1, rW2, pW, pdW,
                                  w1f, w2f, rw1f, rw2f, pjf, pwf);
  k_init<<<N_TOK / 64, 512, 0, stream>>>(x, pjf, pb, itmp, states, tempers, done, meta);
  for (int h = 0; h < NHOPS; ++h) {
    int* cnt_h = meta + h * TN;
    int* cnt_n = meta + (h + 1) * TN;
    int* cur_h = meta + 60 + h * TN;
    int* off_h = meta + 108 + h * (TN + 1);
    k_prefix<<<1, 64, 0, stream>>>(cnt_h, off_h);
    k_scatter<<<N_TOK / TPB, TPB, 0, stream>>>(tempers, done, off_h, cur_h, compact);
    k_hop<<<N_TOK / TOKB + TN, TPB, 0, stream>>>(states, tempers, done, compact, cnt_h, off_h,
        w1f, b1, w2f, b2, rw1f, rb1, rw2f, rb2, cnt_n, hcs[h]);
  }
  float* pred = (float*)d_out;
  float* errp = pred + (size_t)N_TOK * DIN;
  k_pred<<<N_TOK / 64, 512, 0, stream>>>(states, x, pwf, pdb, pred, errp);
}

// Round 13
// 230.556 us; speedup vs baseline: 1.1632x; 1.0489x over previous
//
#include <hip/hip_runtime.h>
#include <cstring>
#include <cmath>
#include <cstdint>

#define N_TOK 65536
#define DIN 128
#define HD 64
#define TN 12
#define ON 3
#define NHOPS 4
#define TPB 256
#define TOKB 64          // tokens per k_hop block (4 waves x 16 tokens)
#define NCAT 13

typedef __attribute__((ext_vector_type(8))) short short8v;     // 8 bf16 frag
typedef __attribute__((ext_vector_type(4))) float f32x4;
typedef __attribute__((ext_vector_type(4))) unsigned short ushort4v;
typedef __attribute__((ext_vector_type(8))) unsigned short ushort8v;
typedef __attribute__((ext_vector_type(2))) unsigned int uint2v;
typedef __attribute__((ext_vector_type(4))) unsigned int uint4v;

struct HopConst {
  float w[TN][ON];
  unsigned ck0, ck1;
  int last_hop;
};

// ---- threefry2x32 (exact JAX semantics) ----
__host__ __device__ __forceinline__ void tf2x32(unsigned k0, unsigned k1,
                                                unsigned x0, unsigned x1,
                                                unsigned& o0, unsigned& o1) {
  unsigned ks2 = k0 ^ k1 ^ 0x1BD11BDAu;
  x0 += k0; x1 += k1;
#define TFR(r) { x0 += x1; x1 = (x1 << (r)) | (x1 >> (32 - (r))); x1 ^= x0; }
  TFR(13) TFR(15) TFR(26) TFR(6)
  x0 += k1;  x1 += ks2 + 1u;
  TFR(17) TFR(29) TFR(16) TFR(24)
  x0 += ks2; x1 += k0 + 2u;
  TFR(13) TFR(15) TFR(26) TFR(6)
  x0 += k0;  x1 += k1 + 3u;
  TFR(17) TFR(29) TFR(16) TFR(24)
  x0 += k1;  x1 += ks2 + 4u;
  TFR(13) TFR(15) TFR(26) TFR(6)
  x0 += ks2; x1 += k0 + 5u;
#undef TFR
  o0 = x0; o1 = x1;
}
__host__ __device__ __forceinline__ unsigned tf_bits32(unsigned k0, unsigned k1, unsigned j) {
  unsigned o0, o1;
  tf2x32(k0, k1, 0u, j, o0, o1);
  return o0 ^ o1;
}

// ---- bf16x3 splitting (scalar path, used by k_init/k_pred/k_wprep) ----
__host__ __device__ __forceinline__ unsigned short bf16r(float v) {
  unsigned u = __builtin_bit_cast(unsigned, v);
  return (unsigned short)((u + 0x7fffu + ((u >> 16) & 1u)) >> 16);
}
__host__ __device__ __forceinline__ float bf2f(unsigned short s) {
  return __builtin_bit_cast(float, ((unsigned)s) << 16);
}
__host__ __device__ __forceinline__ void split3(float v, unsigned short& a,
                                                unsigned short& b, unsigned short& c) {
  a = bf16r(v); float r = v - bf2f(a);
  b = bf16r(r); r -= bf2f(b);
  c = bf16r(r);
}

// ---- pair split via v_cvt_pk_bf16_f32 (RNE, packed output = stored layout) ----
__device__ __forceinline__ void cvtpk3(float v0, float v1,
                                       unsigned& q0, unsigned& q1, unsigned& q2) {
  unsigned p0, p1, p2;
  asm("v_cvt_pk_bf16_f32 %0, %1, %2" : "=v"(p0) : "v"(v0), "v"(v1));
  const float a0 = __builtin_bit_cast(float, p0 << 16);
  const float a1 = __builtin_bit_cast(float, p0 & 0xffff0000u);
  const float r0 = v0 - a0, r1 = v1 - a1;
  asm("v_cvt_pk_bf16_f32 %0, %1, %2" : "=v"(p1) : "v"(r0), "v"(r1));
  const float b0 = __builtin_bit_cast(float, p1 << 16);
  const float b1 = __builtin_bit_cast(float, p1 & 0xffff0000u);
  const float s0 = r0 - b0, s1 = r1 - b1;
  asm("v_cvt_pk_bf16_f32 %0, %1, %2" : "=v"(p2) : "v"(s0), "v"(s1));
  q0 = p0; q1 = p1; q2 = p2;
}

// ---- kernels ----

// init: states = x @ proj_W + proj_b via bf16x3 MFMA; tempers/done/histogram
__global__ __launch_bounds__(512, 4) void k_init(
    const float* __restrict__ x, const unsigned short* __restrict__ pjf,
    const float* __restrict__ pb, const int* __restrict__ itemp,
    float* __restrict__ states, int* __restrict__ tempers,
    int* __restrict__ done, int* __restrict__ cnt0)
{
  __shared__ unsigned short sX[3 * 64 * 128];  // 48KB x splits
  __shared__ float sOut[64 * 64];              // 16KB out
  __shared__ int lcnt[TN];
  const int tid = threadIdx.x;
  const int lane = tid & 63;
  const int w = __builtin_amdgcn_readfirstlane(tid >> 6);
  const int mgrp = w & 1, ngrp = w >> 1;       // 2 feat-halves x 4 tok-quarters
  const int bstart = blockIdx.x * 64;

  // stage x (coalesced): thread = (tok=tid>>3, c0=tid&7), 16 k each
  {
    const int tok = tid >> 3, c0 = tid & 7;
    const float* xr = x + (size_t)(bstart + tok) * DIN + c0 * 16;
    float v[16];
    #pragma unroll
    for (int q = 0; q < 4; ++q) {
      const float4 f = *(const float4*)(xr + q * 4);
      v[q*4] = f.x; v[q*4+1] = f.y; v[q*4+2] = f.z; v[q*4+3] = f.w;
    }
    unsigned short sp[3][16];
    #pragma unroll
    for (int i = 0; i < 16; ++i) split3(v[i], sp[0][i], sp[1][i], sp[2][i]);
    #pragma unroll
    for (int s = 0; s < 3; ++s)
      #pragma unroll
      for (int jj = 0; jj < 2; ++jj) {
        ushort8v u;
        #pragma unroll
        for (int i = 0; i < 8; ++i) u[i] = sp[s][jj * 8 + i];
        const int chunk = (2 * c0 + jj) ^ (tok & 7);
        *(ushort8v*)(sX + s * 8192 + tok * 128 + chunk * 8) = u;
      }
  }
  if (tid < TN) lcnt[tid] = 0;
  __syncthreads();

  const f32x4 zf = {0.0f, 0.0f, 0.0f, 0.0f};
  const int tok16 = (lane & 15) + 16 * ngrp;
  short8v bf[3][4];
  #pragma unroll
  for (int s = 0; s < 3; ++s)
    #pragma unroll
    for (int kc = 0; kc < 4; ++kc) {
      const int chunk = (4 * kc + (lane >> 4)) ^ (tok16 & 7);
      bf[s][kc] = *(const short8v*)(sX + s * 8192 + tok16 * 128 + chunk * 8);
    }
  f32x4 acc[2] = {zf, zf};
  #pragma unroll
  for (int sw = 0; sw < 3; ++sw) {
    short8v a[2][4];
    #pragma unroll
    for (int mt = 0; mt < 2; ++mt)
      #pragma unroll
      for (int kc = 0; kc < 4; ++kc)
        a[mt][kc] = *(const short8v*)(pjf +
            (size_t)((sw * 4 + (2 * mgrp + mt)) * 4 + kc) * 512 + lane * 8);
    #pragma unroll
    for (int sa = 0; sa < 3; ++sa) {
      if (sw + sa > 2) continue;
      #pragma unroll
      for (int mt = 0; mt < 2; ++mt)
        #pragma unroll
        for (int kc = 0; kc < 4; ++kc)
          acc[mt] = __builtin_amdgcn_mfma_f32_16x16x32_bf16(
              a[mt][kc], bf[sa][kc], acc[mt], 0, 0, 0);
    }
  }

  // D + bias -> swizzled f32 LDS
  #pragma unroll
  for (int mt = 0; mt < 2; ++mt) {
    const int mt2 = 2 * mgrp + mt;
    const int j0 = 16 * mt2 + 4 * (lane >> 4);
    const float4 bv = *(const float4*)(pb + j0);
    const float bb[4] = {bv.x, bv.y, bv.z, bv.w};
    f32x4 vv;
    #pragma unroll
    for (int r = 0; r < 4; ++r) vv[r] = acc[mt][r] + bb[r];
    const int chunk = (4 * mt2 + (lane >> 4)) ^ (tok16 & 15);
    *(f32x4*)(sOut + tok16 * 64 + chunk * 4) = vv;
  }
  __syncthreads();

  // coalesced states write-back
  {
    const int tok = tid >> 3, c0 = tid & 7;
    const int n = bstart + tok;
    float* wr = states + (size_t)n * HD;
    #pragma unroll
    for (int q = 0; q < 2; ++q) {
      const int c = c0 + 8 * q;
      const int cs = c ^ (tok & 15);
      *(float4*)(wr + c * 4) = *(const float4*)(sOut + tok * 64 + cs * 4);
    }
  }
  if (tid < 64) {
    const int n = bstart + tid;
    const int t = itemp[n];
    tempers[n] = t;
    done[n] = 0;
    atomicAdd(&lcnt[t], 1);
  }
  __syncthreads();
  if (tid < TN && lcnt[tid] > 0) atomicAdd(&cnt0[tid], lcnt[tid]);
}

// one-time: split weights to bf16x3 in MFMA A-frag order.
// A-frag: frag(s, mtile, kc, lane) holds A[m=16*mtile+(lane&15)][k=32*kc+8*(lane>>4)+i]
__global__ __launch_bounds__(TPB) void k_wprep(
    const float* __restrict__ W1, const float* __restrict__ W2,
    const float* __restrict__ rW1, const float* __restrict__ rW2,
    const float* __restrict__ pjW, const float* __restrict__ pdW,
    unsigned short* __restrict__ w1f, unsigned short* __restrict__ w2f,
    unsigned short* __restrict__ rw1f, unsigned short* __restrict__ rw2f,
    unsigned short* __restrict__ pjf, unsigned short* __restrict__ pwf)
{
  const int idx = blockIdx.x * TPB + threadIdx.x;
  const int NU1 = TN * ON * 4 * 2 * 64;   // 18432
  const int NU2 = 4 * 2 * 64;             // 512
  const int NU3 = 2 * 64;                 // 128
  const int NU4 = 4 * 4 * 64;             // 1024 proj_W (4 mt x 4 kc)
  const int NU5 = 8 * 2 * 64;             // 1024 pred_W (8 mt x 2 kc)
  if (idx < NU1) {
    const int lane = idx & 63, kc = (idx >> 6) & 1, mt = (idx >> 7) & 3, mat = idx >> 9;
    const int j = 16 * mt + (lane & 15);
    const int h0 = 32 * kc + 8 * (lane >> 4);
    const float* s1 = W1 + (size_t)mat * 4096;
    const float* s2 = W2 + (size_t)mat * 4096;
    #pragma unroll
    for (int i = 0; i < 8; ++i) {
      unsigned short a0, a1, a2;
      const size_t base = (size_t)mat * 12288 + (size_t)(mt * 2 + kc) * 512 + lane * 8 + i;
      split3(s1[(h0 + i) * 64 + j], a0, a1, a2);
      w1f[base] = a0; w1f[base + 4096] = a1; w1f[base + 8192] = a2;
      split3(s2[(h0 + i) * 64 + j], a0, a1, a2);
      w2f[base] = a0; w2f[base + 4096] = a1; w2f[base + 8192] = a2;
    }
  } else if (idx < NU1 + NU2) {
    const int u = idx - NU1;
    const int lane = u & 63, kc = (u >> 6) & 1, mt = (u >> 7) & 3;
    const int j = 16 * mt + (lane & 15);
    const int h0 = 32 * kc + 8 * (lane >> 4);
    #pragma unroll
    for (int i = 0; i < 8; ++i) {
      unsigned short a0, a1, a2;
      const size_t base = (size_t)(mt * 2 + kc) * 512 + lane * 8 + i;
      split3(rW1[(h0 + i) * 64 + j], a0, a1, a2);
      rw1f[base] = a0; rw1f[base + 4096] = a1; rw1f[base + 8192] = a2;
    }
  } else if (idx < NU1 + NU2 + NU3) {
    const int u = idx - NU1 - NU2;
    const int lane = u & 63, kc = (u >> 6) & 1;
    const int c = lane & 15;
    const int h0 = 32 * kc + 8 * (lane >> 4);
    #pragma unroll
    for (int i = 0; i < 8; ++i) {
      unsigned short a0, a1, a2;
      const float v = (c < NCAT) ? rW2[(h0 + i) * NCAT + c] : 0.0f;
      split3(v, a0, a1, a2);
      const size_t base = (size_t)kc * 512 + lane * 8 + i;
      rw2f[base] = a0; rw2f[base + 1024] = a1; rw2f[base + 2048] = a2;
    }
  } else if (idx < NU1 + NU2 + NU3 + NU4) {
    const int u = idx - (NU1 + NU2 + NU3);
    const int lane = u & 63, kc = (u >> 6) & 3, mt = u >> 8;
    const int j = 16 * mt + (lane & 15);
    const int k0 = 32 * kc + 8 * (lane >> 4);
    #pragma unroll
    for (int i = 0; i < 8; ++i) {
      unsigned short a0, a1, a2;
      split3(pjW[(size_t)(k0 + i) * 64 + j], a0, a1, a2);
      const size_t base = (size_t)(mt * 4 + kc) * 512 + lane * 8 + i;
      pjf[base] = a0; pjf[base + 8192] = a1; pjf[base + 16384] = a2;
    }
  } else if (idx < NU1 + NU2 + NU3 + NU4 + NU5) {
    const int u = idx - (NU1 + NU2 + NU3 + NU4);
    const int lane = u & 63, kc = (u >> 6) & 1, mt = u >> 7;
    const int d = 16 * mt + (lane & 15);
    const int h0 = 32 * kc + 8 * (lane >> 4);
    #pragma unroll
    for (int i = 0; i < 8; ++i) {
      unsigned short a0, a1, a2;
      split3(pdW[(size_t)(h0 + i) * 128 + d], a0, a1, a2);
      const size_t base = (size_t)(mt * 2 + kc) * 512 + lane * 8 + i;
      pwf[base] = a0; pwf[base + 8192] = a1; pwf[base + 16384] = a2;
    }
  }
}

__global__ void k_prefix(const int* __restrict__ cnt, int* __restrict__ offp) {
  if (threadIdx.x == 0 && blockIdx.x == 0) {
    int o = 0;
    for (int t = 0; t < TN; ++t) { offp[t] = o; o += (cnt[t] + TOKB - 1) & ~(TOKB - 1); }
    offp[TN] = o;
  }
}

__global__ __launch_bounds__(TPB) void k_scatter(
    const int* __restrict__ tempers, const int* __restrict__ done,
    const int* __restrict__ offp, int* __restrict__ cursor, int* __restrict__ compact)
{
  __shared__ int lcnt[TN], lbase[TN];
  const int tid = threadIdx.x;
  if (tid < TN) lcnt[tid] = 0;
  __syncthreads();
  const int n = blockIdx.x * TPB + tid;
  int t = -1, lpos = 0;
  if (!done[n]) { t = tempers[n]; lpos = atomicAdd(&lcnt[t], 1); }
  __syncthreads();
  if (tid < TN && lcnt[tid] > 0) lbase[tid] = atomicAdd(&cursor[tid], lcnt[tid]);
  __syncthreads();
  if (t >= 0) compact[offp[t] + lbase[t] + lpos] = n;
}

// ---- wave-local helpers (16 tokens x 64 features per wave) ----

// scratch layout per split s: idx = n*64 + ((f>>3)^(n&7))*8 + (f&7)  (u16 units)
__device__ __forceinline__ void load_bf(const unsigned short* src, int lane, short8v bf[3][2]) {
  const int n = lane & 15, g = lane >> 4;
  #pragma unroll
  for (int s = 0; s < 3; ++s)
    #pragma unroll
    for (int kc = 0; kc < 2; ++kc) {
      const int chunk = (4 * kc + g) ^ (n & 7);
      bf[s][kc] = *(const short8v*)(src + s * 1024 + n * 64 + chunk * 8);
    }
}

// 6-pass bf16x3 MFMA, 4 m-tiles x 16 tokens. All 24 A-frags loaded upfront:
// one vmcnt wait per matrix op. MFMA order (sw,sa,mt,kc) identical to R10/R12.
__device__ __forceinline__ void mfma_all4(const unsigned short* __restrict__ Ag,
                                          const short8v bf[3][2], int lane, f32x4 acc[4]) {
  short8v a[24];
  #pragma unroll
  for (int u = 0; u < 24; ++u)
    a[u] = *(const short8v*)(Ag + (size_t)u * 512 + lane * 8);
  #pragma unroll
  for (int sw = 0; sw < 3; ++sw)
    #pragma unroll
    for (int sa = 0; sa < 3; ++sa) {
      if (sw + sa > 2) continue;
      #pragma unroll
      for (int mt = 0; mt < 4; ++mt)
        #pragma unroll
        for (int kc = 0; kc < 2; ++kc)
          acc[mt] = __builtin_amdgcn_mfma_f32_16x16x32_bf16(
              a[sw * 8 + mt * 2 + kc], bf[sa][kc], acc[mt], 0, 0, 0);
    }
}

// bias + relu + cvt_pk split -> wave-local swizzled scratch
__device__ __forceinline__ void store4_rb(const f32x4 acc[4], const float* __restrict__ bias,
                                          unsigned short* dst, int lane) {
  const int n = lane & 15, g = lane >> 4;
  #pragma unroll
  for (int mt = 0; mt < 4; ++mt) {
    const int j0 = 16 * mt + 4 * g;
    const float4 bv = *(const float4*)(bias + j0);
    const float v0 = fmaxf(acc[mt][0] + bv.x, 0.0f);
    const float v1 = fmaxf(acc[mt][1] + bv.y, 0.0f);
    const float v2 = fmaxf(acc[mt][2] + bv.z, 0.0f);
    const float v3 = fmaxf(acc[mt][3] + bv.w, 0.0f);
    unsigned q00, q01, q02, q10, q11, q12;
    cvtpk3(v0, v1, q00, q01, q02);
    cvtpk3(v2, v3, q10, q11, q12);
    const int idx = n * 64 + ((2 * mt + (g >> 1)) ^ (n & 7)) * 8 + 4 * (g & 1);
    *(uint2v*)(dst + idx)        = uint2v{q00, q10};
    *(uint2v*)(dst + 1024 + idx) = uint2v{q01, q11};
    *(uint2v*)(dst + 2048 + idx) = uint2v{q02, q12};
  }
}

// raw cvt_pk split -> scratch (no bias/relu) for routing input
__device__ __forceinline__ void store4_raw(const f32x4 acc[4], unsigned short* dst, int lane) {
  const int n = lane & 15, g = lane >> 4;
  #pragma unroll
  for (int mt = 0; mt < 4; ++mt) {
    unsigned q00, q01, q02, q10, q11, q12;
    cvtpk3(acc[mt][0], acc[mt][1], q00, q01, q02);
    cvtpk3(acc[mt][2], acc[mt][3], q10, q11, q12);
    const int idx = n * 64 + ((2 * mt + (g >> 1)) ^ (n & 7)) * 8 + 4 * (g & 1);
    *(uint2v*)(dst + idx)        = uint2v{q00, q10};
    *(uint2v*)(dst + 1024 + idx) = uint2v{q01, q11};
    *(uint2v*)(dst + 2048 + idx) = uint2v{q02, q12};
  }
}

// main per-hop kernel: barrier-free per-wave pipeline. Each wave owns 16
// tokens x all 64 features; exchange via private 6KB LDS scratch (lgkmcnt
// only, no __syncthreads).
__global__ __launch_bounds__(TPB, 2) void k_hop(
    float* __restrict__ states, int* __restrict__ tempers, int* __restrict__ done,
    const int* __restrict__ compact, const int* __restrict__ cnt,
    const int* __restrict__ offp,
    const unsigned short* __restrict__ w1f, const float* __restrict__ b1,
    const unsigned short* __restrict__ w2f, const float* __restrict__ b2,
    const unsigned short* __restrict__ rw1f, const float* __restrict__ rb1,
    const unsigned short* __restrict__ rw2f, const float* __restrict__ rb2,
    int* __restrict__ cnt_next, HopConst hc)
{
  __shared__ unsigned short scr[4][3072];   // 24KB: 6KB private scratch per wave
  __shared__ int lcnt[TN];

  const int tid = threadIdx.x;
  const int lane = tid & 63;
  const int wid = __builtin_amdgcn_readfirstlane(tid >> 6);
  unsigned short* ws = scr[wid];
  const int bstart = blockIdx.x * TOKB;
  if (bstart >= offp[TN]) return;
  if (tid < TN) lcnt[tid] = 0;
  int tt = 0;
  #pragma unroll
  for (int i = 1; i < TN; ++i) if (bstart >= offp[i]) tt = i;
  const int t = __builtin_amdgcn_readfirstlane(tt);
  const int cntt = cnt[t];
  const int n = lane & 15, g = lane >> 4;
  const int pos = bstart + wid * 16 + n;
  const bool act = (pos - offp[t]) < cntt;
  const int tok = compact[act ? pos : offp[t]];

  // ---- stage states in-register via cvt_pk split ----
  short8v bx[3][2];
  {
    const float* sr = states + (size_t)tok * HD;
    float va[8], vb[8];
    #pragma unroll
    for (int q = 0; q < 2; ++q) {
      const float4 f0 = *(const float4*)(sr + 8 * g + q * 4);
      const float4 f1 = *(const float4*)(sr + 32 + 8 * g + q * 4);
      va[q*4] = f0.x; va[q*4+1] = f0.y; va[q*4+2] = f0.z; va[q*4+3] = f0.w;
      vb[q*4] = f1.x; vb[q*4+1] = f1.y; vb[q*4+2] = f1.z; vb[q*4+3] = f1.w;
    }
    uint4v wa[3], wb[3];
    #pragma unroll
    for (int i = 0; i < 4; ++i) {
      unsigned pa0, pa1, pa2, pb0, pb1, pb2;
      cvtpk3(va[2*i], va[2*i+1], pa0, pa1, pa2);
      cvtpk3(vb[2*i], vb[2*i+1], pb0, pb1, pb2);
      wa[0][i] = pa0; wa[1][i] = pa1; wa[2][i] = pa2;
      wb[0][i] = pb0; wb[1][i] = pb1; wb[2][i] = pb2;
    }
    #pragma unroll
    for (int s = 0; s < 3; ++s) {
      bx[s][0] = __builtin_bit_cast(short8v, wa[s]);
      bx[s][1] = __builtin_bit_cast(short8v, wb[s]);
    }
  }
  __syncthreads();   // lcnt init visible before any sampling adds

  const f32x4 zf = {0.0f, 0.0f, 0.0f, 0.0f};
  f32x4 out4[4] = {zf, zf, zf, zf};

  #pragma unroll 1
  for (int o = 0; o < ON; ++o) {
    const int mat = t * ON + o;
    f32x4 acc[4] = {zf, zf, zf, zf};
    mfma_all4(w1f + (size_t)mat * 12288, bx, lane, acc);
    store4_rb(acc, b1 + mat * 64, ws, lane);          // h1 splits -> wave scratch
    short8v bh[3][2];
    load_bf(ws, lane, bh);                            // lgkmcnt-ordered, wave-local
    f32x4 acc2[4] = {zf, zf, zf, zf};
    mfma_all4(w2f + (size_t)mat * 12288, bh, lane, acc2);
    const float wo = hc.w[t][o];
    #pragma unroll
    for (int mt = 0; mt < 4; ++mt) {
      const float4 bv = *(const float4*)(b2 + mat * 64 + 16 * mt + 4 * g);
      const float bb[4] = {bv.x, bv.y, bv.z, bv.w};
      #pragma unroll
      for (int r = 0; r < 4; ++r)
        out4[mt][r] = fmaf(wo, fmaxf(acc2[mt][r] + bb[r], 0.0f), out4[mt][r]);
    }
  }

  // ---- states write-back (direct, 16B per store) ----
  if (act) {
    float* wr = states + (size_t)tok * HD;
    #pragma unroll
    for (int mt = 0; mt < 4; ++mt) {
      float4 v; v.x = out4[mt][0]; v.y = out4[mt][1]; v.z = out4[mt][2]; v.w = out4[mt][3];
      *(float4*)(wr + 16 * mt + 4 * g) = v;
    }
  }

  if (!hc.last_hop) {
    // ---- routing: r1 = relu(out @ rW1 + rb1) ----
    store4_raw(out4, ws, lane);
    short8v bo[3][2];
    load_bf(ws, lane, bo);
    f32x4 accr[4] = {zf, zf, zf, zf};
    mfma_all4(rw1f, bo, lane, accr);
    store4_rb(accr, rb1, ws, lane);
    short8v br[3][2];
    load_bf(ws, lane, br);

    // ---- logits = r1 @ rW2 (1 m-tile of 16 cats) ----
    f32x4 lg = zf;
    #pragma unroll
    for (int sw = 0; sw < 3; ++sw) {
      short8v a2[2];
      #pragma unroll
      for (int kc = 0; kc < 2; ++kc)
        a2[kc] = *(const short8v*)(rw2f + (size_t)(sw * 2 + kc) * 512 + lane * 8);
      #pragma unroll
      for (int sa = 0; sa < 3; ++sa) {
        if (sw + sa > 2) continue;
        #pragma unroll
        for (int kc = 0; kc < 2; ++kc)
          lg = __builtin_amdgcn_mfma_f32_16x16x32_bf16(a2[kc], br[sa][kc], lg, 0, 0, 0);
      }
    }

    // ---- gumbel-argmax: lane handles cats 4g..4g+3 of its token ----
    float best = -3.0e38f; int bc = 0;
    const unsigned jbase = (unsigned)tok * (unsigned)NCAT;
    #pragma unroll
    for (int r = 0; r < 4; ++r) {
      const int c = 4 * g + r;
      if (c < NCAT) {
        const unsigned bits = tf_bits32(hc.ck0, hc.ck1, jbase + (unsigned)c);
        const float u = __uint_as_float((bits >> 9) | 0x3f800000u) - 1.0f;
        float val = u + 1.17549435e-38f;
        val = fmaxf(val, 1.17549435e-38f);
        const float gum = -logf(-logf(val));
        const float sc = lg[r] + rb2[c] + gum;
        if (sc > best) { best = sc; bc = c; }
      }
    }
    #pragma unroll
    for (int off = 16; off <= 32; off <<= 1) {
      const float ob = __shfl_xor(best, off, 64);
      const int oc = __shfl_xor(bc, off, 64);
      if (ob > best || (ob == best && oc < bc)) { best = ob; bc = oc; }
    }
    if (g == 0 && act) {
      const int nt = bc < (TN - 1) ? bc : (TN - 1);
      tempers[tok] = nt;
      if (bc == TN) done[tok] = 1;
      else atomicAdd(&lcnt[nt], 1);
    }
    __syncthreads();
    if (tid < TN && lcnt[tid] > 0) atomicAdd(&cnt_next[tid], lcnt[tid]);
  }
}

// pred = states @ pred_W + pred_b via bf16x3 MFMA; fused err reduction
__global__ __launch_bounds__(512, 4) void k_pred(
    const float* __restrict__ states, const float* __restrict__ x,
    const unsigned short* __restrict__ pwf, const float* __restrict__ pdb,
    float* __restrict__ pred, float* __restrict__ err)
{
  __shared__ unsigned short sX[3 * 64 * 64];   // 24KB states splits
  __shared__ float sP[64 * 128];               // 32KB pred
  const int tid = threadIdx.x;
  const int lane = tid & 63;
  const int w = __builtin_amdgcn_readfirstlane(tid >> 6);
  const int mgrp = w & 3, ngrp = w >> 2;       // 4 d-quarters x 2 tok-halves
  const int bstart = blockIdx.x * 64;

  // stage states (coalesced): thread = (tok=tid>>3, c0=tid&7), 8 h each
  {
    const int tok = tid >> 3, c0 = tid & 7;
    const float* sr = states + (size_t)(bstart + tok) * HD + c0 * 8;
    float v[8];
    #pragma unroll
    for (int q = 0; q < 2; ++q) {
      const float4 f = *(const float4*)(sr + q * 4);
      v[q*4] = f.x; v[q*4+1] = f.y; v[q*4+2] = f.z; v[q*4+3] = f.w;
    }
    unsigned short sp[3][8];
    #pragma unroll
    for (int i = 0; i < 8; ++i) split3(v[i], sp[0][i], sp[1][i], sp[2][i]);
    const int chunk = c0 ^ (tok & 7);
    #pragma unroll
    for (int s = 0; s < 3; ++s) {
      ushort8v u;
      #pragma unroll
      for (int i = 0; i < 8; ++i) u[i] = sp[s][i];
      *(ushort8v*)(sX + s * 4096 + tok * 64 + chunk * 8) = u;
    }
  }
  __syncthreads();

  const f32x4 zf = {0.0f, 0.0f, 0.0f, 0.0f};
  short8v bf[3][2][2];
  #pragma unroll
  for (int s = 0; s < 3; ++s)
    #pragma unroll
    for (int nt = 0; nt < 2; ++nt)
      #pragma unroll
      for (int kc = 0; kc < 2; ++kc) {
        const int tk = (lane & 15) + 16 * (2 * ngrp + nt);
        const int chunk = (4 * kc + (lane >> 4)) ^ (tk & 7);
        bf[s][nt][kc] = *(const short8v*)(sX + s * 4096 + tk * 64 + chunk * 8);
      }

  f32x4 acc[2][2] = {{zf, zf}, {zf, zf}};
  #pragma unroll
  for (int sw = 0; sw < 3; ++sw) {
    short8v a[2][2];
    #pragma unroll
    for (int mt = 0; mt < 2; ++mt)
      #pragma unroll
      for (int kc = 0; kc < 2; ++kc)
        a[mt][kc] = *(const short8v*)(pwf +
            (size_t)((sw * 8 + (2 * mgrp + mt)) * 2 + kc) * 512 + lane * 8);
    #pragma unroll
    for (int sa = 0; sa < 3; ++sa) {
      if (sw + sa > 2) continue;
      #pragma unroll
      for (int mt = 0; mt < 2; ++mt)
        #pragma unroll
        for (int nt = 0; nt < 2; ++nt)
          #pragma unroll
          for (int kc = 0; kc < 2; ++kc)
            acc[mt][nt] = __builtin_amdgcn_mfma_f32_16x16x32_bf16(
                a[mt][kc], bf[sa][nt][kc], acc[mt][nt], 0, 0, 0);
    }
  }

  // D + bias -> swizzled f32 LDS
  #pragma unroll
  for (int mt = 0; mt < 2; ++mt) {
    const int mt2 = 2 * mgrp + mt;
    const int d0 = 16 * mt2 + 4 * (lane >> 4);
    const float4 bv = *(const float4*)(pdb + d0);
    const float bb[4] = {bv.x, bv.y, bv.z, bv.w};
    #pragma unroll
    for (int nt = 0; nt < 2; ++nt) {
      const int tok = (lane & 15) + 16 * (2 * ngrp + nt);
      f32x4 vv;
      #pragma unroll
      for (int r = 0; r < 4; ++r) vv[r] = acc[mt][nt][r] + bb[r];
      const int chunk = (d0 >> 2) ^ (tok & 7);
      *(f32x4*)(sP + tok * 128 + chunk * 4) = vv;
    }
  }
  __syncthreads();

  // coalesced pred write + fused err
  {
    const int tok = tid >> 3, c0 = tid & 7;
    const int n = bstart + tok;
    const float* xr = x + (size_t)n * DIN;
    float* pr = pred + (size_t)n * DIN;
    float s = 0.0f;
    #pragma unroll
    for (int q = 0; q < 4; ++q) {
      const int c = c0 + 8 * q;
      const int cs = c ^ (tok & 7);
      const f32x4 pv = *(const f32x4*)(sP + tok * 128 + cs * 4);
      const float4 xv = *(const float4*)(xr + c * 4);
      float4 ov; ov.x = pv[0]; ov.y = pv[1]; ov.z = pv[2]; ov.w = pv[3];
      *(float4*)(pr + c * 4) = ov;
      const float e0 = pv[0] - xv.x, e1 = pv[1] - xv.y, e2 = pv[2] - xv.z, e3 = pv[3] - xv.w;
      s += e0 * e0 + e1 * e1 + e2 * e2 + e3 * e3;
    }
    s += __shfl_xor(s, 1, 64);
    s += __shfl_xor(s, 2, 64);
    s += __shfl_xor(s, 4, 64);
    if (c0 == 0) err[n] = s * (1.0f / 128.0f);
  }
}

// ---- host-side RNG constant derivation ----
static float host_erfinv(float xf) {
  double x = xf;
  double w = -log1p(-x * x);
  double p;
  if (w < 5.0) {
    w -= 2.5;
    p = 2.81022636e-08;          p = 3.43273939e-07 + p * w;
    p = -3.5233877e-06 + p * w;  p = -4.39150654e-06 + p * w;
    p = 0.00021858087 + p * w;   p = -0.00125372503 + p * w;
    p = -0.00417768164 + p * w;  p = 0.246640727 + p * w;
    p = 1.50140941 + p * w;
  } else {
    w = sqrt(w) - 3.0;
    p = -0.000200214257;         p = 0.000100950558 + p * w;
    p = 0.00134934322 + p * w;   p = -0.00367342844 + p * w;
    p = 0.00573950773 + p * w;   p = -0.0076224613 + p * w;
    p = 0.00943887047 + p * w;   p = 1.00167406 + p * w;
    p = 2.83297682 + p * w;
  }
  return (float)(p * x);
}

static void build_hops(HopConst* hcs) {
  const float lo = nextafterf(-1.0f, 0.0f);
  const unsigned rk0 = 0u, rk1 = 42u;
  for (int hop = 0; hop < NHOPS; ++hop) {
    unsigned hk0, hk1;
    tf2x32(rk0, rk1, 0u, (unsigned)hop, hk0, hk1);
    for (int t = 0; t < TN; ++t) {
      unsigned tk0, tk1;
      tf2x32(hk0, hk1, 0u, (unsigned)t, tk0, tk1);
      double nrm[3];
      for (int i = 0; i < 3; ++i) {
        const unsigned bits = tf_bits32(tk0, tk1, (unsigned)i);
        unsigned ub = (bits >> 9) | 0x3f800000u;
        float f; memcpy(&f, &ub, 4);
        const float u01 = f - 1.0f;
        float val = u01 * 2.0f + lo;
        if (val < lo) val = lo;
        const float ef = host_erfinv(val);
        nrm[i] = (double)(1.41421356f * ef);
      }
      const double m = fmax(nrm[0], fmax(nrm[1], nrm[2]));
      const double e0 = exp(nrm[0] - m), e1 = exp(nrm[1] - m), e2 = exp(nrm[2] - m);
      const double s = e0 + e1 + e2;
      hcs[hop].w[t][0] = (float)(e0 / s);
      hcs[hop].w[t][1] = (float)(e1 / s);
      hcs[hop].w[t][2] = (float)(e2 / s);
    }
    unsigned ck0, ck1;
    tf2x32(hk0, hk1, 0u, 10000u, ck0, ck1);
    hcs[hop].ck0 = ck0; hcs[hop].ck1 = ck1;
    hcs[hop].last_hop = (hop == NHOPS - 1) ? 1 : 0;
  }
}

extern "C" void kernel_launch(void* const* d_in, const int* in_sizes, int n_in,
                              void* d_out, int out_size, void* d_ws, size_t ws_size,
                              hipStream_t stream) {
  (void)in_sizes; (void)n_in; (void)out_size; (void)ws_size;
  const float* x    = (const float*)d_in[0];
  const float* pW   = (const float*)d_in[1];
  const float* pb   = (const float*)d_in[2];
  const float* W1   = (const float*)d_in[3];
  const float* b1   = (const float*)d_in[4];
  const float* W2   = (const float*)d_in[5];
  const float* b2   = (const float*)d_in[6];
  const float* rW1  = (const float*)d_in[7];
  const float* rb1  = (const float*)d_in[8];
  const float* rW2  = (const float*)d_in[9];
  const float* rb2  = (const float*)d_in[10];
  const float* pdW  = (const float*)d_in[11];
  const float* pdb  = (const float*)d_in[12];
  const int*   itmp = (const int*)d_in[13];

  // ws: [meta 1KB][tempers N][done N][compact N+TN*TOKB][states N*64 f32]
  //     [w1f][w2f][rw1f][rw2f][pjf][pwf] (u16 frag arrays)
  int* meta    = (int*)d_ws;
  int* tempers = (int*)((char*)d_ws + 1024);
  int* done    = tempers + N_TOK;
  int* compact = done + N_TOK;
  float* states = (float*)(compact + N_TOK + TN * TOKB);
  unsigned short* w1f  = (unsigned short*)(states + (size_t)N_TOK * HD);
  unsigned short* w2f  = w1f + (size_t)TN * ON * 12288;
  unsigned short* rw1f = w2f + (size_t)TN * ON * 12288;
  unsigned short* rw2f = rw1f + 12288;
  unsigned short* pjf  = rw2f + 3072;
  unsigned short* pwf  = pjf + 24576;

  HopConst hcs[NHOPS];
  build_hops(hcs);

  hipMemsetAsync(meta, 0, 160 * sizeof(int), stream);
  k_wprep<<<83, TPB, 0, stream>>>(W1, W2, rW1, rW2, pW, pdW,
                                  w1f, w2f, rw1f, rw2f, pjf, pwf);
  k_init<<<N_TOK / 64, 512, 0, stream>>>(x, pjf, pb, itmp, states, tempers, done, meta);
  for (int h = 0; h < NHOPS; ++h) {
    int* cnt_h = meta + h * TN;
    int* cnt_n = meta + (h + 1) * TN;
    int* cur_h = meta + 60 + h * TN;
    int* off_h = meta + 108 + h * (TN + 1);
    k_prefix<<<1, 64, 0, stream>>>(cnt_h, off_h);
    k_scatter<<<N_TOK / TPB, TPB, 0, stream>>>(tempers, done, off_h, cur_h, compact);
    k_hop<<<N_TOK / TOKB + TN, TPB, 0, stream>>>(states, tempers, done, compact, cnt_h, off_h,
        w1f, b1, w2f, b2, rw1f, rb1, rw2f, rb2, cnt_n, hcs[h]);
  }
  float* pred = (float*)d_out;
  float* errp = pred + (size_t)N_TOK * DIN;
  k_pred<<<N_TOK / 64, 512, 0, stream>>>(states, x, pwf, pdb, pred, errp);
}